// Round 6
// baseline (380.482 us; speedup 1.0000x reference)
//
#include <hip/hip_runtime.h>
#include <hip/hip_bf16.h>

// SelfAttention (B=4, C=128, H=W=64), fp32 I/O.
// out[b,c,i] = X[b,c,i] + sum_j exp(S[i,j]) * rinv_j * V[j,c],
//   S = Q K^T, rinv_j = 1/sum_i exp(S[i,j])   (softmax over query axis)
// fp32-faithful via split-bf16 (hi+lo) 3-term MFMA emulation, 32x32x16 MFMA.

typedef unsigned short u16;
typedef __attribute__((ext_vector_type(8))) __bf16 bf16x8;
typedef __attribute__((ext_vector_type(8))) unsigned short us8;
typedef __attribute__((ext_vector_type(4))) float f32x4;
typedef __attribute__((ext_vector_type(16))) float f32x16;

#define NB 4
#define CH 128
#define NP 4096
#define JSPL 8   // attn j-splits (partials into xacc)
#define ISPL 8   // stats i-splits (partials into colpart)

__device__ __forceinline__ float bf2f(u16 b){ union{float f;unsigned u;}v; v.u=((unsigned)b)<<16; return v.f; }
__device__ __forceinline__ u16 f2bf(float f){ union{float f;unsigned u;}v; v.f=f; unsigned r=v.u + 0x7FFFu + ((v.u>>16)&1u); return (u16)(r>>16); }

__device__ __forceinline__ f32x4 mfma16(bf16x8 a, bf16x8 b, f32x4 c){
  return __builtin_amdgcn_mfma_f32_16x16x32_bf16(a, b, c, 0, 0, 0);
}
__device__ __forceinline__ f32x16 mfma32(bf16x8 a, bf16x8 b, f32x16 c){
  return __builtin_amdgcn_mfma_f32_32x32x16_bf16(a, b, c, 0, 0, 0);
}
__device__ __forceinline__ bf16x8 ld8(const u16* p){
  union { us8 u; bf16x8 b; } v; v.u = *(const us8*)p; return v.b;
}
__device__ __forceinline__ void split8(const float* p, bf16x8& h, bf16x8& l){
  union { us8 u; bf16x8 b; } uh, ul;
  #pragma unroll
  for (int e=0;e<8;++e){
    float f = p[e];
    u16 hb = f2bf(f);
    uh.u[e] = hb;
    ul.u[e] = f2bf(f - bf2f(hb));
  }
  h = uh.b; l = ul.b;
}
// pack (a,b) -> bf16 pair dword (hi) + residual bf16 pair dword (lo), RNE
__device__ __forceinline__ void pksplit(float a, float b, unsigned& dhi, unsigned& dlo){
  float2 f2; f2.x = a; f2.y = b;
  __hip_bfloat162 hb = __float22bfloat162_rn(f2);
  unsigned u; __builtin_memcpy(&u, &hb, 4);
  dhi = u;
  union{unsigned x;float f;} ca, cb;
  ca.x = u << 16; cb.x = u & 0xFFFF0000u;
  float2 g2; g2.x = a - ca.f; g2.y = b - cb.f;
  __hip_bfloat162 lb = __float22bfloat162_rn(g2);
  __builtin_memcpy(&dlo, &lb, 4);
}
__device__ __forceinline__ void gll16(const void* g, void* l){
  __builtin_amdgcn_global_load_lds((const __attribute__((address_space(1))) void*)g,
                                   (__attribute__((address_space(3))) void*)l, 16, 0, 0);
}

// ---------------------------------------------------------------------------
// Kernel 0: pre-split the three 128x128 weight matrices into bf16 hi/lo.
// ---------------------------------------------------------------------------
__global__ __launch_bounds__(256) void wsplit_kernel(
    const float* __restrict__ Wq, const float* __restrict__ Wk,
    const float* __restrict__ Wv, u16* __restrict__ Whi, u16* __restrict__ Wlo)
{
  const int m = blockIdx.y;
  const float* W = (m==0) ? Wq : (m==1) ? Wk : Wv;
  int i = blockIdx.x*256 + threadIdx.x;
  float f = W[i];
  u16 hb = f2bf(f);
  Whi[m*CH*CH + i] = hb;
  Wlo[m*CH*CH + i] = f2bf(f - bf2f(hb));
}

// ---------------------------------------------------------------------------
// Kernel 1: projections (one wave per 16-pixel tile), 16x16x32 MFMA.
// Q/K stored [b][i][ch] hi/lo; V stored transposed [b][c][j] hi/lo.
// ---------------------------------------------------------------------------
__global__ __launch_bounds__(64) void proj_kernel(
    const float* __restrict__ X,
    const u16* __restrict__ Whi, const u16* __restrict__ Wlo,
    const float* __restrict__ bq, const float* __restrict__ bk,
    const float* __restrict__ bv,
    u16* __restrict__ Qhi, u16* __restrict__ Qlo,
    u16* __restrict__ Khi, u16* __restrict__ Klo,
    u16* __restrict__ Vthi, u16* __restrict__ Vtlo)
{
  __shared__ float XT[16][CH+4];
  const int b = blockIdx.y, p0 = blockIdx.x*16, lane = threadIdx.x;
  #pragma unroll
  for (int h=0; h<2; ++h){
    int c = lane + h*64;
    const float* src = X + ((size_t)b*CH + c)*NP + p0;
    #pragma unroll
    for (int v4=0; v4<4; ++v4){
      f32x4 v = *(const f32x4*)(src + v4*4);
      #pragma unroll
      for (int p=0;p<4;++p) XT[v4*4+p][c] = v[p];
    }
  }
  __syncthreads();
  const int l15 = lane&15, quad = lane>>4;
  bf16x8 xh[4], xl[4];
  #pragma unroll
  for (int s=0;s<4;++s) split8(&XT[l15][s*32+quad*8], xh[s], xl[s]);

  const float* bm[2] = {bq, bk};
  u16* OH[2] = {Qhi, Khi};
  u16* OL[2] = {Qlo, Klo};
  #pragma unroll
  for (int m=0;m<2;++m){
    const u16* WH = Whi + m*CH*CH;
    const u16* WL = Wlo + m*CH*CH;
    #pragma unroll
    for (int nt=0;nt<8;++nt){
      f32x4 a = {0.f,0.f,0.f,0.f};
      #pragma unroll
      for (int s=0;s<4;++s){
        size_t g = (size_t)(nt*16+l15)*CH + s*32 + quad*8;
        bf16x8 wh = ld8(&WH[g]), wl = ld8(&WL[g]);
        a = mfma16(xh[s], wl, a);
        a = mfma16(xl[s], wh, a);
        a = mfma16(xh[s], wh, a);
      }
      int o = nt*16 + l15;
      float bias = bm[m][o];
      #pragma unroll
      for (int r=0;r<4;++r){
        int i = p0 + quad*4 + r;
        float q = a[r] + bias;
        u16 hb = f2bf(q);
        size_t idx = ((size_t)b*NP + i)*CH + o;
        OH[m][idx] = hb;
        OL[m][idx] = f2bf(q - bf2f(hb));
      }
    }
  }
  const u16* WH = Whi + 2*CH*CH;
  const u16* WL = Wlo + 2*CH*CH;
  #pragma unroll
  for (int mt=0;mt<8;++mt){
    f32x4 a = {0.f,0.f,0.f,0.f};
    #pragma unroll
    for (int s=0;s<4;++s){
      size_t g = (size_t)(mt*16+l15)*CH + s*32 + quad*8;
      bf16x8 wh = ld8(&WH[g]), wl = ld8(&WL[g]);
      a = mfma16(wh, xl[s], a);
      a = mfma16(wl, xh[s], a);
      a = mfma16(wh, xh[s], a);
    }
    #pragma unroll
    for (int r=0;r<4;++r){
      int co = mt*16 + quad*4 + r;
      float v = a[r] + bv[co];
      u16 hb = f2bf(v);
      size_t idx = ((size_t)b*CH + co)*NP + p0 + l15;
      Vthi[idx] = hb;
      Vtlo[idx] = f2bf(v - bf2f(hb));
    }
  }
}

// ---------------------------------------------------------------------------
// Kernel 2: partial column sums via S^T = K Q^T with 32x32x16 MFMA.
// Wave owns 32 j (K frags register-resident). Q chunks (32 i) staged in LDS
// via global_load_lds, double-buffered, shared by all 4 waves.
// colpart[isplit][b][j] = sum_{i in chunk} exp(S[i][j])
// ---------------------------------------------------------------------------
__global__ __launch_bounds__(256,4) void stats_kernel(
    const u16* __restrict__ Qhi, const u16* __restrict__ Qlo,
    const u16* __restrict__ Khi, const u16* __restrict__ Klo,
    float* __restrict__ colpart)
{
  __shared__ u16 SQ[2][2][32*CH];   // [buf][hi/lo][chunk(c16)*32 + row] * 8
  const int b = blockIdx.z, isplit = blockIdx.y;
  const int tid = threadIdx.x, lane = tid&63, w = tid>>6;
  const int l31 = lane&31, h = lane>>5;
  const int j0w = blockIdx.x*128 + w*32;

  // staging coords: 512 slots of 16B, 2 per thread
  const int slot0 = w*128 + lane, slot1 = slot0 + 64;
  const int qr0 = slot0&31, qc0 = slot0>>5, qr1 = slot1&31, qc1 = slot1>>5;
  const size_t qg0 = ((size_t)b*NP + qr0)*CH + qc0*8;
  const size_t qg1 = ((size_t)b*NP + qr1)*CH + qc1*8;
  const int lof0 = slot0*8, lof1 = slot1*8;

  // K fragments register-resident: A[m=j=l31][k=ks*16+h*8+e]
  bf16x8 kh[8], kl[8];
  #pragma unroll
  for (int ks=0;ks<8;++ks){
    size_t g = ((size_t)b*NP + j0w + l31)*CH + ks*16 + h*8;
    kh[ks] = ld8(&Khi[g]);
    kl[ks] = ld8(&Klo[g]);
  }

  const int ibase = isplit*(NP/ISPL);
  // stage chunk 0
  gll16(&Qhi[qg0 + (size_t)ibase*CH], &SQ[0][0][lof0]);
  gll16(&Qhi[qg1 + (size_t)ibase*CH], &SQ[0][0][lof1]);
  gll16(&Qlo[qg0 + (size_t)ibase*CH], &SQ[0][1][lof0]);
  gll16(&Qlo[qg1 + (size_t)ibase*CH], &SQ[0][1][lof1]);
  __syncthreads();

  float scol[16];
  #pragma unroll
  for (int r=0;r<16;++r) scol[r] = 0.f;

  const int NCH = (NP/ISPL)/32;     // 16 chunks
  for (int ic=0; ic<NCH; ++ic){
    if (ic < NCH-1){
      int nb = (ic+1)&1;
      size_t iofs = (size_t)(ibase + (ic+1)*32)*CH;
      gll16(&Qhi[qg0 + iofs], &SQ[nb][0][lof0]);
      gll16(&Qhi[qg1 + iofs], &SQ[nb][0][lof1]);
      gll16(&Qlo[qg0 + iofs], &SQ[nb][1][lof0]);
      gll16(&Qlo[qg1 + iofs], &SQ[nb][1][lof1]);
    }
    const int cb = ic&1;
    const u16* Qh = &SQ[cb][0][0];
    const u16* Ql = &SQ[cb][1][0];
    f32x16 s;
    #pragma unroll
    for (int r=0;r<16;++r) s[r] = 0.f;
    #pragma unroll
    for (int ks=0;ks<8;++ks){
      int o = (ks*2+h)*256 + l31*8;      // B[k][n=i=l31]
      bf16x8 qbh = ld8(&Qh[o]);
      bf16x8 qbl = ld8(&Ql[o]);
      s = mfma32(kh[ks], qbl, s);
      s = mfma32(kl[ks], qbh, s);
      s = mfma32(kh[ks], qbh, s);
    }
    #pragma unroll
    for (int r=0;r<16;++r) scol[r] += __expf(s[r]);
    __syncthreads();
  }
  // reduce over the 32 i-lanes (same h keeps same j)
  #pragma unroll
  for (int m=1; m<32; m<<=1){
    #pragma unroll
    for (int r=0;r<16;++r) scol[r] += __shfl_xor(scol[r], m);
  }
  if (l31 == 0){
    #pragma unroll
    for (int r=0;r<16;++r){
      int j = j0w + (r&3) + 8*(r>>2) + 4*h;
      colpart[((size_t)(isplit*NB + b))*NP + j] = scol[r];
    }
  }
}

// ---------------------------------------------------------------------------
// Kernel 3: in-place V' = rinv_j * V (hi/lo re-split), rinv computed inline
// from the ISPL colpart partials.
// ---------------------------------------------------------------------------
__global__ __launch_bounds__(256) void scalev_kernel(
    u16* __restrict__ Vthi, u16* __restrict__ Vtlo,
    const float* __restrict__ colpart)
{
  size_t t = (size_t)blockIdx.x*256 + threadIdx.x;
  size_t base = t*8;
  int bc = (int)(base >> 12);
  int b  = bc >> 7;
  int j0 = (int)(base & (NP-1));
  f32x4 s0 = {0.f,0.f,0.f,0.f}, s1 = {0.f,0.f,0.f,0.f};
  #pragma unroll
  for (int k=0;k<ISPL;++k){
    const float* cp = &colpart[((size_t)(k*NB + b))*NP + j0];
    f32x4 a0 = *(const f32x4*)cp;
    f32x4 a1 = *(const f32x4*)(cp+4);
    #pragma unroll
    for (int e=0;e<4;++e){ s0[e]+=a0[e]; s1[e]+=a1[e]; }
  }
  us8 hh = *(const us8*)&Vthi[base];
  us8 ll = *(const us8*)&Vtlo[base];
  us8 oh, ol;
  #pragma unroll
  for (int e=0;e<8;++e){
    float r = 1.0f / (e<4 ? s0[e] : s1[e-4]);
    float v = (bf2f(hh[e]) + bf2f(ll[e])) * r;
    u16 hb = f2bf(v);
    oh[e] = hb;
    ol[e] = f2bf(v - bf2f(hb));
  }
  *(us8*)&Vthi[base] = oh;
  *(us8*)&Vtlo[base] = ol;
}

// ---------------------------------------------------------------------------
// Kernel 4: flash attn, 32x32x16, S^T formulation, in-register P transpose,
// global_load_lds double-buffered staging, one barrier per j-tile.
// 512-thread blocks: 8 waves share each staged K/V tile (2 blocks/CU,
// 4 waves/SIMD).
// ---------------------------------------------------------------------------
__global__ __launch_bounds__(512,4) void attn_kernel(
    const u16* __restrict__ Qhi, const u16* __restrict__ Qlo,
    const u16* __restrict__ Khi, const u16* __restrict__ Klo,
    const u16* __restrict__ Vthi, const u16* __restrict__ Vtlo,
    float* __restrict__ xacc)
{
  __shared__ u16 SK[2][2][32*CH];    // [buf][hi/lo][chunk(c16)*32 + row] * 8
  __shared__ u16 SV[2][2][4*CH*8];   // [buf][hi/lo][chunk(c4)*128 + row] * 8
  const int b = blockIdx.z, jsplit = blockIdx.y;
  const int tid = threadIdx.x, lane = tid&63, w = tid>>6;
  const int l31 = lane&31, h = lane>>5;
  const int i0w = blockIdx.x*256 + w*32;
  const bool hb1 = (h != 0);

  // staging: 512 slots of 16B per array, 1 per thread
  const int slot = tid;
  const int kr = slot&31, kc = slot>>5;
  const int vr = slot&127, vc = slot>>7;
  const size_t kg = ((size_t)b*NP + kr)*CH + kc*8;
  const size_t vg = ((size_t)b*CH + vr)*NP + vc*8;
  const int lof = slot*8;

  bf16x8 qh[8], ql[8];
  #pragma unroll
  for (int ks=0;ks<8;++ks){
    size_t g = ((size_t)b*NP + i0w + l31)*CH + ks*16 + h*8;
    qh[ks] = ld8(&Qhi[g]); ql[ks] = ld8(&Qlo[g]);
  }
  f32x16 acc[4];
  #pragma unroll
  for (int mt=0;mt<4;++mt)
    #pragma unroll
    for (int r=0;r<16;++r) acc[mt][r] = 0.f;

  const int jbase = jsplit*(NP/JSPL);
  {
    int j0 = jbase;
    gll16(&Khi[kg + (size_t)j0*CH], &SK[0][0][lof]);
    gll16(&Klo[kg + (size_t)j0*CH], &SK[0][1][lof]);
    gll16(&Vthi[vg + j0], &SV[0][0][lof]);
    gll16(&Vtlo[vg + j0], &SV[0][1][lof]);
  }
  __syncthreads();

  const int NJT = (NP/JSPL)/32;     // 16 j-tiles
  for (int jt=0; jt<NJT; ++jt){
    if (jt < NJT-1){
      int nb = (jt+1)&1, j0 = jbase + (jt+1)*32;
      gll16(&Khi[kg + (size_t)j0*CH], &SK[nb][0][lof]);
      gll16(&Klo[kg + (size_t)j0*CH], &SK[nb][1][lof]);
      gll16(&Vthi[vg + j0], &SV[nb][0][lof]);
      gll16(&Vtlo[vg + j0], &SV[nb][1][lof]);
    }
    const int cb = jt&1;
    const u16* Kh = &SK[cb][0][0];
    const u16* Kl = &SK[cb][1][0];
    const u16* Vh = &SV[cb][0][0];
    const u16* Vl = &SV[cb][1][0];

    f32x16 s;
    #pragma unroll
    for (int r=0;r<16;++r) s[r] = 0.f;
    #pragma unroll
    for (int ks=0;ks<8;++ks){
      int o = (ks*2+h)*256 + l31*8;
      bf16x8 ah = ld8(&Kh[o]);
      bf16x8 al = ld8(&Kl[o]);
      s = mfma32(ah, ql[ks], s);
      s = mfma32(al, qh[ks], s);
      s = mfma32(ah, qh[ks], s);
    }
    float p[16];
    #pragma unroll
    for (int r=0;r<16;++r) p[r] = __expf(s[r]);

    #pragma unroll
    for (int t=0;t<2;++t){
      unsigned hA,lA,hB,lB,hC,lC,hD,lD;
      pksplit(p[8*t+0], p[8*t+1], hA, lA);
      pksplit(p[8*t+2], p[8*t+3], hB, lB);
      pksplit(p[8*t+4], p[8*t+5], hC, lC);
      pksplit(p[8*t+6], p[8*t+7], hD, lD);
      unsigned s0h = hb1? hA:hC, s1h = hb1? hB:hD;
      unsigned s0l = hb1? lA:lC, s1l = hb1? lB:lD;
      unsigned r0h = __shfl_xor(s0h, 32), r1h = __shfl_xor(s1h, 32);
      unsigned r0l = __shfl_xor(s0l, 32), r1l = __shfl_xor(s1l, 32);
      unsigned dh[4], dl[4];
      dh[0] = hb1? r0h : hA;  dh[1] = hb1? r1h : hB;
      dh[2] = hb1? hC  : r0h; dh[3] = hb1? hD  : r1h;
      dl[0] = hb1? r0l : lA;  dl[1] = hb1? r1l : lB;
      dl[2] = hb1? lC  : r0l; dl[3] = hb1? lD  : r1l;
      bf16x8 Bh, Bl;
      __builtin_memcpy(&Bh, dh, 16);
      __builtin_memcpy(&Bl, dl, 16);
      #pragma unroll
      for (int mt=0;mt<4;++mt){
        int o = (t*2+h)*1024 + (mt*32+l31)*8;
        bf16x8 vh = ld8(&Vh[o]);
        bf16x8 vl = ld8(&Vl[o]);
        acc[mt] = mfma32(vh, Bl, acc[mt]);
        acc[mt] = mfma32(vl, Bh, acc[mt]);
        acc[mt] = mfma32(vh, Bh, acc[mt]);
      }
    }
    __syncthreads();
  }
  float* xp = xacc + (size_t)b*CH*NP;
  #pragma unroll
  for (int mt=0;mt<4;++mt){
    #pragma unroll
    for (int r=0;r<16;++r){
      int c = mt*32 + (r&3) + 8*(r>>2) + 4*h;
      atomicAdd(&xp[(size_t)c*NP + i0w + l31], acc[mt][r]);
    }
  }
}

// ---------------------------------------------------------------------------
// Kernel 5: out = X + xacc
// ---------------------------------------------------------------------------
__global__ __launch_bounds__(256) void final_kernel(
    const float* __restrict__ X, const float* __restrict__ xacc,
    float* __restrict__ out)
{
  size_t idx = ((size_t)blockIdx.x*256 + threadIdx.x)*4;
  f32x4 x = *(const f32x4*)&X[idx];
  f32x4 a = *(const f32x4*)&xacc[idx];
  f32x4 r;
  #pragma unroll
  for (int e=0;e<4;++e) r[e] = x[e] + a[e];
  *(f32x4*)&out[idx] = r;
}

extern "C" void kernel_launch(void* const* d_in, const int* in_sizes, int n_in,
                              void* d_out, int out_size, void* d_ws, size_t ws_size,
                              hipStream_t stream)
{
  const float* X  = (const float*)d_in[0];
  const float* Wq = (const float*)d_in[1];
  const float* bq = (const float*)d_in[2];
  const float* Wk = (const float*)d_in[3];
  const float* bk = (const float*)d_in[4];
  const float* Wv = (const float*)d_in[5];
  const float* bv = (const float*)d_in[6];
  float* outp = (float*)d_out;

  const size_t n = (size_t)NB*NP*CH;        // 2,097,152
  u16* Qhi = (u16*)d_ws;
  u16* Qlo = Qhi + n;
  u16* Khi = Qlo + n;
  u16* Klo = Khi + n;
  u16* Vthi = Klo + n;
  u16* Vtlo = Vthi + n;
  u16* Whi  = Vtlo + n;
  u16* Wlo  = Whi + 3*CH*CH;
  float* colpart = (float*)(Wlo + 3*CH*CH);     // ISPL*NB*NP
  float* xacc    = colpart + (size_t)ISPL*NB*NP; // NB*CH*NP fp32 = 8 MB

  hipMemsetAsync(xacc, 0, n*sizeof(float), stream);

  wsplit_kernel<<<dim3(CH*CH/256, 3),      256, 0, stream>>>(Wq, Wk, Wv, Whi, Wlo);
  proj_kernel  <<<dim3(NP/16, NB),          64, 0, stream>>>(X, Whi, Wlo, bq, bk, bv,
                                                             Qhi,Qlo, Khi,Klo, Vthi,Vtlo);
  stats_kernel <<<dim3(NP/128, ISPL, NB),  256, 0, stream>>>(Qhi,Qlo, Khi,Klo, colpart);
  scalev_kernel<<<dim3(n/(256*8)),         256, 0, stream>>>(Vthi, Vtlo, colpart);
  attn_kernel  <<<dim3(NP/256, JSPL, NB),  512, 0, stream>>>(Qhi,Qlo, Khi,Klo,
                                                             Vthi,Vtlo, xacc);
  final_kernel <<<dim3(n/(256*4)),         256, 0, stream>>>(X, xacc, outp);
}

// Round 7
// 315.319 us; speedup vs baseline: 1.2067x; 1.2067x over previous
//
#include <hip/hip_runtime.h>
#include <hip/hip_bf16.h>

// SelfAttention (B=4, C=128, H=W=64), fp32 I/O.
// out[b,c,i] = X[b,c,i] + sum_j exp(S[i,j]) * rinv_j * V[j,c],
//   S = Q K^T, rinv_j = 1/sum_i exp(S[i,j])   (softmax over query axis)
// fp32-faithful via split-bf16 (hi+lo) 3-term MFMA emulation, 32x32x16 MFMA.

typedef unsigned short u16;
typedef __attribute__((ext_vector_type(8))) __bf16 bf16x8;
typedef __attribute__((ext_vector_type(8))) unsigned short us8;
typedef __attribute__((ext_vector_type(4))) float f32x4;
typedef __attribute__((ext_vector_type(16))) float f32x16;

#define NB 4
#define CH 128
#define NP 4096
#define JSPL 8   // attn j-splits (partials into xacc)
#define ISPL 8   // stats i-splits (partials into colpart)

__device__ __forceinline__ float bf2f(u16 b){ union{float f;unsigned u;}v; v.u=((unsigned)b)<<16; return v.f; }
__device__ __forceinline__ u16 f2bf(float f){ union{float f;unsigned u;}v; v.f=f; unsigned r=v.u + 0x7FFFu + ((v.u>>16)&1u); return (u16)(r>>16); }

__device__ __forceinline__ f32x4 mfma16(bf16x8 a, bf16x8 b, f32x4 c){
  return __builtin_amdgcn_mfma_f32_16x16x32_bf16(a, b, c, 0, 0, 0);
}
__device__ __forceinline__ f32x16 mfma32(bf16x8 a, bf16x8 b, f32x16 c){
  return __builtin_amdgcn_mfma_f32_32x32x16_bf16(a, b, c, 0, 0, 0);
}
__device__ __forceinline__ bf16x8 ld8(const u16* p){
  union { us8 u; bf16x8 b; } v; v.u = *(const us8*)p; return v.b;
}
__device__ __forceinline__ void split8(const float* p, bf16x8& h, bf16x8& l){
  union { us8 u; bf16x8 b; } uh, ul;
  #pragma unroll
  for (int e=0;e<8;++e){
    float f = p[e];
    u16 hb = f2bf(f);
    uh.u[e] = hb;
    ul.u[e] = f2bf(f - bf2f(hb));
  }
  h = uh.b; l = ul.b;
}
// pack (a,b) -> bf16 pair dword (hi) + residual bf16 pair dword (lo), RNE
__device__ __forceinline__ void pksplit(float a, float b, unsigned& dhi, unsigned& dlo){
  float2 f2; f2.x = a; f2.y = b;
  __hip_bfloat162 hb = __float22bfloat162_rn(f2);
  unsigned u; __builtin_memcpy(&u, &hb, 4);
  dhi = u;
  union{unsigned x;float f;} ca, cb;
  ca.x = u << 16; cb.x = u & 0xFFFF0000u;
  float2 g2; g2.x = a - ca.f; g2.y = b - cb.f;
  __hip_bfloat162 lb = __float22bfloat162_rn(g2);
  __builtin_memcpy(&dlo, &lb, 4);
}
__device__ __forceinline__ void gll16(const void* g, void* l){
  __builtin_amdgcn_global_load_lds((const __attribute__((address_space(1))) void*)g,
                                   (__attribute__((address_space(3))) void*)l, 16, 0, 0);
}

// ---------------------------------------------------------------------------
// Kernel 0: pre-split the three 128x128 weight matrices into bf16 hi/lo.
// ---------------------------------------------------------------------------
__global__ __launch_bounds__(256) void wsplit_kernel(
    const float* __restrict__ Wq, const float* __restrict__ Wk,
    const float* __restrict__ Wv, u16* __restrict__ Whi, u16* __restrict__ Wlo)
{
  const int m = blockIdx.y;
  const float* W = (m==0) ? Wq : (m==1) ? Wk : Wv;
  int i = blockIdx.x*256 + threadIdx.x;
  float f = W[i];
  u16 hb = f2bf(f);
  Whi[m*CH*CH + i] = hb;
  Wlo[m*CH*CH + i] = f2bf(f - bf2f(hb));
}

// ---------------------------------------------------------------------------
// Kernel 1: projections (one wave per 16-pixel tile), 16x16x32 MFMA.
// Q/K stored [b][i][ch] hi/lo; V stored transposed [b][c][j] hi/lo.
// ---------------------------------------------------------------------------
__global__ __launch_bounds__(64) void proj_kernel(
    const float* __restrict__ X,
    const u16* __restrict__ Whi, const u16* __restrict__ Wlo,
    const float* __restrict__ bq, const float* __restrict__ bk,
    const float* __restrict__ bv,
    u16* __restrict__ Qhi, u16* __restrict__ Qlo,
    u16* __restrict__ Khi, u16* __restrict__ Klo,
    u16* __restrict__ Vthi, u16* __restrict__ Vtlo)
{
  __shared__ float XT[16][CH+4];
  const int b = blockIdx.y, p0 = blockIdx.x*16, lane = threadIdx.x;
  #pragma unroll
  for (int h=0; h<2; ++h){
    int c = lane + h*64;
    const float* src = X + ((size_t)b*CH + c)*NP + p0;
    #pragma unroll
    for (int v4=0; v4<4; ++v4){
      f32x4 v = *(const f32x4*)(src + v4*4);
      #pragma unroll
      for (int p=0;p<4;++p) XT[v4*4+p][c] = v[p];
    }
  }
  __syncthreads();
  const int l15 = lane&15, quad = lane>>4;
  bf16x8 xh[4], xl[4];
  #pragma unroll
  for (int s=0;s<4;++s) split8(&XT[l15][s*32+quad*8], xh[s], xl[s]);

  const float* bm[2] = {bq, bk};
  u16* OH[2] = {Qhi, Khi};
  u16* OL[2] = {Qlo, Klo};
  #pragma unroll
  for (int m=0;m<2;++m){
    const u16* WH = Whi + m*CH*CH;
    const u16* WL = Wlo + m*CH*CH;
    #pragma unroll
    for (int nt=0;nt<8;++nt){
      f32x4 a = {0.f,0.f,0.f,0.f};
      #pragma unroll
      for (int s=0;s<4;++s){
        size_t g = (size_t)(nt*16+l15)*CH + s*32 + quad*8;
        bf16x8 wh = ld8(&WH[g]), wl = ld8(&WL[g]);
        a = mfma16(xh[s], wl, a);
        a = mfma16(xl[s], wh, a);
        a = mfma16(xh[s], wh, a);
      }
      int o = nt*16 + l15;
      float bias = bm[m][o];
      #pragma unroll
      for (int r=0;r<4;++r){
        int i = p0 + quad*4 + r;
        float q = a[r] + bias;
        u16 hb = f2bf(q);
        size_t idx = ((size_t)b*NP + i)*CH + o;
        OH[m][idx] = hb;
        OL[m][idx] = f2bf(q - bf2f(hb));
      }
    }
  }
  const u16* WH = Whi + 2*CH*CH;
  const u16* WL = Wlo + 2*CH*CH;
  #pragma unroll
  for (int mt=0;mt<8;++mt){
    f32x4 a = {0.f,0.f,0.f,0.f};
    #pragma unroll
    for (int s=0;s<4;++s){
      size_t g = (size_t)(mt*16+l15)*CH + s*32 + quad*8;
      bf16x8 wh = ld8(&WH[g]), wl = ld8(&WL[g]);
      a = mfma16(wh, xl[s], a);
      a = mfma16(wl, xh[s], a);
      a = mfma16(wh, xh[s], a);
    }
    #pragma unroll
    for (int r=0;r<4;++r){
      int co = mt*16 + quad*4 + r;
      float v = a[r] + bv[co];
      u16 hb = f2bf(v);
      size_t idx = ((size_t)b*CH + co)*NP + p0 + l15;
      Vthi[idx] = hb;
      Vtlo[idx] = f2bf(v - bf2f(hb));
    }
  }
}

// ---------------------------------------------------------------------------
// Kernel 2: partial column sums via S^T = K Q^T with 32x32x16 MFMA.
// Wave owns 32 j (K frags register-resident). Q chunks (32 i) staged in LDS
// via global_load_lds, double-buffered, shared by all 4 waves.
// colpart[isplit][b][j] = sum_{i in chunk} exp(S[i][j])
// ---------------------------------------------------------------------------
__global__ __launch_bounds__(256,3) void stats_kernel(
    const u16* __restrict__ Qhi, const u16* __restrict__ Qlo,
    const u16* __restrict__ Khi, const u16* __restrict__ Klo,
    float* __restrict__ colpart)
{
  __shared__ u16 SQ[2][2][32*CH];   // [buf][hi/lo][chunk(c16)*32 + row] * 8
  const int b = blockIdx.z, isplit = blockIdx.y;
  const int tid = threadIdx.x, lane = tid&63, w = tid>>6;
  const int l31 = lane&31, h = lane>>5;
  const int j0w = blockIdx.x*128 + w*32;

  // staging coords: 512 slots of 16B, 2 per thread
  const int slot0 = w*128 + lane, slot1 = slot0 + 64;
  const int qr0 = slot0&31, qc0 = slot0>>5, qr1 = slot1&31, qc1 = slot1>>5;
  const size_t qg0 = ((size_t)b*NP + qr0)*CH + qc0*8;
  const size_t qg1 = ((size_t)b*NP + qr1)*CH + qc1*8;
  const int lof0 = slot0*8, lof1 = slot1*8;

  // K fragments register-resident: A[m=j=l31][k=ks*16+h*8+e]
  bf16x8 kh[8], kl[8];
  #pragma unroll
  for (int ks=0;ks<8;++ks){
    size_t g = ((size_t)b*NP + j0w + l31)*CH + ks*16 + h*8;
    kh[ks] = ld8(&Khi[g]);
    kl[ks] = ld8(&Klo[g]);
  }

  const int ibase = isplit*(NP/ISPL);
  // stage chunk 0
  gll16(&Qhi[qg0 + (size_t)ibase*CH], &SQ[0][0][lof0]);
  gll16(&Qhi[qg1 + (size_t)ibase*CH], &SQ[0][0][lof1]);
  gll16(&Qlo[qg0 + (size_t)ibase*CH], &SQ[0][1][lof0]);
  gll16(&Qlo[qg1 + (size_t)ibase*CH], &SQ[0][1][lof1]);
  __syncthreads();

  float scol[16];
  #pragma unroll
  for (int r=0;r<16;++r) scol[r] = 0.f;

  const int NCH = (NP/ISPL)/32;     // 16 chunks
  for (int ic=0; ic<NCH; ++ic){
    if (ic < NCH-1){
      int nb = (ic+1)&1;
      size_t iofs = (size_t)(ibase + (ic+1)*32)*CH;
      gll16(&Qhi[qg0 + iofs], &SQ[nb][0][lof0]);
      gll16(&Qhi[qg1 + iofs], &SQ[nb][0][lof1]);
      gll16(&Qlo[qg0 + iofs], &SQ[nb][1][lof0]);
      gll16(&Qlo[qg1 + iofs], &SQ[nb][1][lof1]);
    }
    const int cb = ic&1;
    const u16* Qh = &SQ[cb][0][0];
    const u16* Ql = &SQ[cb][1][0];
    f32x16 s;
    #pragma unroll
    for (int r=0;r<16;++r) s[r] = 0.f;
    #pragma unroll
    for (int ks=0;ks<8;++ks){
      int o = (ks*2+h)*256 + l31*8;      // B[k][n=i=l31]
      bf16x8 qbh = ld8(&Qh[o]);
      bf16x8 qbl = ld8(&Ql[o]);
      s = mfma32(kh[ks], qbl, s);
      s = mfma32(kl[ks], qbh, s);
      s = mfma32(kh[ks], qbh, s);
    }
    #pragma unroll
    for (int r=0;r<16;++r) scol[r] += __expf(s[r]);
    __syncthreads();
  }
  // reduce over the 32 i-lanes (same h keeps same j)
  #pragma unroll
  for (int m=1; m<32; m<<=1){
    #pragma unroll
    for (int r=0;r<16;++r) scol[r] += __shfl_xor(scol[r], m);
  }
  if (l31 == 0){
    #pragma unroll
    for (int r=0;r<16;++r){
      int j = j0w + (r&3) + 8*(r>>2) + 4*h;
      colpart[((size_t)(isplit*NB + b))*NP + j] = scol[r];
    }
  }
}

// ---------------------------------------------------------------------------
// Kernel 3: in-place V' = rinv_j * V (hi/lo re-split), rinv computed inline
// from the ISPL colpart partials.
// ---------------------------------------------------------------------------
__global__ __launch_bounds__(256) void scalev_kernel(
    u16* __restrict__ Vthi, u16* __restrict__ Vtlo,
    const float* __restrict__ colpart)
{
  size_t t = (size_t)blockIdx.x*256 + threadIdx.x;
  size_t base = t*8;
  int bc = (int)(base >> 12);
  int b  = bc >> 7;
  int j0 = (int)(base & (NP-1));
  f32x4 s0 = {0.f,0.f,0.f,0.f}, s1 = {0.f,0.f,0.f,0.f};
  #pragma unroll
  for (int k=0;k<ISPL;++k){
    const float* cp = &colpart[((size_t)(k*NB + b))*NP + j0];
    f32x4 a0 = *(const f32x4*)cp;
    f32x4 a1 = *(const f32x4*)(cp+4);
    #pragma unroll
    for (int e=0;e<4;++e){ s0[e]+=a0[e]; s1[e]+=a1[e]; }
  }
  us8 hh = *(const us8*)&Vthi[base];
  us8 ll = *(const us8*)&Vtlo[base];
  us8 oh, ol;
  #pragma unroll
  for (int e=0;e<8;++e){
    float r = 1.0f / (e<4 ? s0[e] : s1[e-4]);
    float v = (bf2f(hh[e]) + bf2f(ll[e])) * r;
    u16 hb = f2bf(v);
    oh[e] = hb;
    ol[e] = f2bf(v - bf2f(hb));
  }
  *(us8*)&Vthi[base] = oh;
  *(us8*)&Vtlo[base] = ol;
}

// ---------------------------------------------------------------------------
// Kernel 4: flash attn, 32x32x16, S^T formulation, in-register P transpose.
// SINGLE-buffered K/V staging (32 KB LDS -> 4 blocks/CU, 16 waves/CU);
// latency hidden by inter-block TLP instead of intra-block double-buffer.
// Two barriers per j-tile: overwrite-guard, then staged-guard (vmcnt drain).
// ---------------------------------------------------------------------------
__global__ __launch_bounds__(256,2) void attn_kernel(
    const u16* __restrict__ Qhi, const u16* __restrict__ Qlo,
    const u16* __restrict__ Khi, const u16* __restrict__ Klo,
    const u16* __restrict__ Vthi, const u16* __restrict__ Vtlo,
    float* __restrict__ xacc)
{
  __shared__ u16 SK[2][32*CH];     // [hi/lo][chunk(c16)*32 + row] * 8   (16 KB)
  __shared__ u16 SV[2][4*CH*8];    // [hi/lo][chunk(c4)*128 + row] * 8   (16 KB)
  const int b = blockIdx.z, jsplit = blockIdx.y;
  const int tid = threadIdx.x, lane = tid&63, w = tid>>6;
  const int l31 = lane&31, h = lane>>5;
  const int i0w = blockIdx.x*128 + w*32;
  const bool hb1 = (h != 0);

  // staging: 512 slots of 16B per array-half, 2 per thread
  const int slot0 = tid, slot1 = tid + 256;
  const int kr0 = slot0&31, kc0 = slot0>>5, kr1 = slot1&31, kc1 = slot1>>5;
  const int vr0 = slot0&127, vc0 = slot0>>7, vr1 = slot1&127, vc1 = slot1>>7;
  const size_t kg0 = ((size_t)b*NP + kr0)*CH + kc0*8;
  const size_t kg1 = ((size_t)b*NP + kr1)*CH + kc1*8;
  const size_t vg0 = ((size_t)b*CH + vr0)*NP + vc0*8;
  const size_t vg1 = ((size_t)b*CH + vr1)*NP + vc1*8;
  const int lof0 = slot0*8, lof1 = slot1*8;

  // Q B-fragments resident: B[k=ks*16+h*8+e][n=i=l31]
  bf16x8 qh[8], ql[8];
  #pragma unroll
  for (int ks=0;ks<8;++ks){
    size_t g = ((size_t)b*NP + i0w + l31)*CH + ks*16 + h*8;
    qh[ks] = ld8(&Qhi[g]); ql[ks] = ld8(&Qlo[g]);
  }
  f32x16 acc[4];
  #pragma unroll
  for (int mt=0;mt<4;++mt)
    #pragma unroll
    for (int r=0;r<16;++r) acc[mt][r] = 0.f;

  const int jbase = jsplit*(NP/JSPL);
  const int NJT = (NP/JSPL)/32;     // 16 j-tiles
  for (int jt=0; jt<NJT; ++jt){
    const int j0 = jbase + jt*32;
    __syncthreads();                 // A: all waves done reading previous tile
    gll16(&Khi[kg0 + (size_t)j0*CH], &SK[0][lof0]);
    gll16(&Khi[kg1 + (size_t)j0*CH], &SK[0][lof1]);
    gll16(&Klo[kg0 + (size_t)j0*CH], &SK[1][lof0]);
    gll16(&Klo[kg1 + (size_t)j0*CH], &SK[1][lof1]);
    gll16(&Vthi[vg0 + j0], &SV[0][lof0]);
    gll16(&Vthi[vg1 + j0], &SV[0][lof1]);
    gll16(&Vtlo[vg0 + j0], &SV[1][lof0]);
    gll16(&Vtlo[vg1 + j0], &SV[1][lof1]);
    __syncthreads();                 // B: staging complete (vmcnt drained)

    const u16* Kh = &SK[0][0];
    const u16* Kl = &SK[1][0];
    const u16* Vh = &SV[0][0];
    const u16* Vl = &SV[1][0];

    // S^T tile: A=K[m=j=l31][k], B=Q  -> C/D: col=i=l31, row=j
    f32x16 s;
    #pragma unroll
    for (int r=0;r<16;++r) s[r] = 0.f;
    #pragma unroll
    for (int ks=0;ks<8;++ks){
      int o = (ks*2+h)*256 + l31*8;
      bf16x8 ah = ld8(&Kh[o]);
      bf16x8 al = ld8(&Kl[o]);
      s = mfma32(ah, ql[ks], s);
      s = mfma32(al, qh[ks], s);
      s = mfma32(ah, qh[ks], s);
    }
    float p[16];
    #pragma unroll
    for (int r=0;r<16;++r) p[r] = __expf(s[r]);

    // two k-tiles of 16 j each: assemble P^T B-frags in-register
    #pragma unroll
    for (int t=0;t<2;++t){
      unsigned hA,lA,hB,lB,hC,lC,hD,lD;
      pksplit(p[8*t+0], p[8*t+1], hA, lA);
      pksplit(p[8*t+2], p[8*t+3], hB, lB);
      pksplit(p[8*t+4], p[8*t+5], hC, lC);
      pksplit(p[8*t+6], p[8*t+7], hD, lD);
      unsigned s0h = hb1? hA:hC, s1h = hb1? hB:hD;
      unsigned s0l = hb1? lA:lC, s1l = hb1? lB:lD;
      unsigned r0h = __shfl_xor(s0h, 32), r1h = __shfl_xor(s1h, 32);
      unsigned r0l = __shfl_xor(s0l, 32), r1l = __shfl_xor(s1l, 32);
      unsigned dh[4], dl[4];
      dh[0] = hb1? r0h : hA;  dh[1] = hb1? r1h : hB;
      dh[2] = hb1? hC  : r0h; dh[3] = hb1? hD  : r1h;
      dl[0] = hb1? r0l : lA;  dl[1] = hb1? r1l : lB;
      dl[2] = hb1? lC  : r0l; dl[3] = hb1? lD  : r1l;
      bf16x8 Bh, Bl;
      __builtin_memcpy(&Bh, dh, 16);
      __builtin_memcpy(&Bl, dl, 16);
      // PV: A = V'^T[m=c][k=j], B = P^T -> acc[c][i]
      #pragma unroll
      for (int mt=0;mt<4;++mt){
        int o = (t*2+h)*1024 + (mt*32+l31)*8;
        bf16x8 vh = ld8(&Vh[o]);
        bf16x8 vl = ld8(&Vl[o]);
        acc[mt] = mfma32(vh, Bl, acc[mt]);
        acc[mt] = mfma32(vl, Bh, acc[mt]);
        acc[mt] = mfma32(vh, Bh, acc[mt]);
      }
    }
  }
  // epilogue: acc[mt][r] = O^T[c][i], c = mt*32+(r&3)+8*(r>>2)+4*h, i = i0w+l31
  float* xp = xacc + (size_t)b*CH*NP;
  #pragma unroll
  for (int mt=0;mt<4;++mt){
    #pragma unroll
    for (int r=0;r<16;++r){
      int c = mt*32 + (r&3) + 8*(r>>2) + 4*h;
      atomicAdd(&xp[(size_t)c*NP + i0w + l31], acc[mt][r]);
    }
  }
}

// ---------------------------------------------------------------------------
// Kernel 5: out = X + xacc
// ---------------------------------------------------------------------------
__global__ __launch_bounds__(256) void final_kernel(
    const float* __restrict__ X, const float* __restrict__ xacc,
    float* __restrict__ out)
{
  size_t idx = ((size_t)blockIdx.x*256 + threadIdx.x)*4;
  f32x4 x = *(const f32x4*)&X[idx];
  f32x4 a = *(const f32x4*)&xacc[idx];
  f32x4 r;
  #pragma unroll
  for (int e=0;e<4;++e) r[e] = x[e] + a[e];
  *(f32x4*)&out[idx] = r;
}

extern "C" void kernel_launch(void* const* d_in, const int* in_sizes, int n_in,
                              void* d_out, int out_size, void* d_ws, size_t ws_size,
                              hipStream_t stream)
{
  const float* X  = (const float*)d_in[0];
  const float* Wq = (const float*)d_in[1];
  const float* bq = (const float*)d_in[2];
  const float* Wk = (const float*)d_in[3];
  const float* bk = (const float*)d_in[4];
  const float* Wv = (const float*)d_in[5];
  const float* bv = (const float*)d_in[6];
  float* outp = (float*)d_out;

  const size_t n = (size_t)NB*NP*CH;        // 2,097,152
  u16* Qhi = (u16*)d_ws;
  u16* Qlo = Qhi + n;
  u16* Khi = Qlo + n;
  u16* Klo = Khi + n;
  u16* Vthi = Klo + n;
  u16* Vtlo = Vthi + n;
  u16* Whi  = Vtlo + n;
  u16* Wlo  = Whi + 3*CH*CH;
  float* colpart = (float*)(Wlo + 3*CH*CH);      // ISPL*NB*NP
  float* xacc    = colpart + (size_t)ISPL*NB*NP; // NB*CH*NP fp32 = 8 MB

  hipMemsetAsync(xacc, 0, n*sizeof(float), stream);

  wsplit_kernel<<<dim3(CH*CH/256, 3),      256, 0, stream>>>(Wq, Wk, Wv, Whi, Wlo);
  proj_kernel  <<<dim3(NP/16, NB),          64, 0, stream>>>(X, Whi, Wlo, bq, bk, bv,
                                                             Qhi,Qlo, Khi,Klo, Vthi,Vtlo);
  stats_kernel <<<dim3(NP/128, ISPL, NB),  256, 0, stream>>>(Qhi,Qlo, Khi,Klo, colpart);
  scalev_kernel<<<dim3(n/(256*8)),         256, 0, stream>>>(Vthi, Vtlo, colpart);
  attn_kernel  <<<dim3(NP/128, JSPL, NB),  256, 0, stream>>>(Qhi,Qlo, Khi,Klo,
                                                             Vthi,Vtlo, xacc);
  final_kernel <<<dim3(n/(256*4)),         256, 0, stream>>>(X, xacc, outp);
}

// Round 8
// 283.706 us; speedup vs baseline: 1.3411x; 1.1114x over previous
//
#include <hip/hip_runtime.h>
#include <hip/hip_bf16.h>

// SelfAttention (B=4, C=128, H=W=64), fp32 I/O.
// out[b,c,i] = X[b,c,i] + sum_j exp(S[i,j]) * rinv_j * V[j,c],
//   S = Q K^T, rinv_j = 1/sum_i exp(S[i,j])   (softmax over query axis)
// fp32-faithful via split-bf16 (hi+lo) 3-term MFMA emulation, 32x32x16 MFMA.
// attn/stats are software-pipelined: S(t+1) MFMAs overlap exp/pack/PV(t).

typedef unsigned short u16;
typedef __attribute__((ext_vector_type(8))) __bf16 bf16x8;
typedef __attribute__((ext_vector_type(8))) unsigned short us8;
typedef __attribute__((ext_vector_type(4))) float f32x4;
typedef __attribute__((ext_vector_type(16))) float f32x16;

#define NB 4
#define CH 128
#define NP 4096
#define JSPL 4   // attn j-splits (partials into xacc)
#define ISPL 8   // stats i-splits (partials into colpart)

__device__ __forceinline__ float bf2f(u16 b){ union{float f;unsigned u;}v; v.u=((unsigned)b)<<16; return v.f; }
__device__ __forceinline__ u16 f2bf(float f){ union{float f;unsigned u;}v; v.f=f; unsigned r=v.u + 0x7FFFu + ((v.u>>16)&1u); return (u16)(r>>16); }

__device__ __forceinline__ f32x4 mfma16(bf16x8 a, bf16x8 b, f32x4 c){
  return __builtin_amdgcn_mfma_f32_16x16x32_bf16(a, b, c, 0, 0, 0);
}
__device__ __forceinline__ f32x16 mfma32(bf16x8 a, bf16x8 b, f32x16 c){
  return __builtin_amdgcn_mfma_f32_32x32x16_bf16(a, b, c, 0, 0, 0);
}
__device__ __forceinline__ bf16x8 ld8(const u16* p){
  union { us8 u; bf16x8 b; } v; v.u = *(const us8*)p; return v.b;
}
__device__ __forceinline__ void split8(const float* p, bf16x8& h, bf16x8& l){
  union { us8 u; bf16x8 b; } uh, ul;
  #pragma unroll
  for (int e=0;e<8;++e){
    float f = p[e];
    u16 hb = f2bf(f);
    uh.u[e] = hb;
    ul.u[e] = f2bf(f - bf2f(hb));
  }
  h = uh.b; l = ul.b;
}
// pack (a,b) -> bf16 pair dword (hi) + residual bf16 pair dword (lo), RNE
__device__ __forceinline__ void pksplit(float a, float b, unsigned& dhi, unsigned& dlo){
  float2 f2; f2.x = a; f2.y = b;
  __hip_bfloat162 hb = __float22bfloat162_rn(f2);
  unsigned u; __builtin_memcpy(&u, &hb, 4);
  dhi = u;
  union{unsigned x;float f;} ca, cb;
  ca.x = u << 16; cb.x = u & 0xFFFF0000u;
  float2 g2; g2.x = a - ca.f; g2.y = b - cb.f;
  __hip_bfloat162 lb = __float22bfloat162_rn(g2);
  __builtin_memcpy(&dlo, &lb, 4);
}
__device__ __forceinline__ void gll16(const void* g, void* l){
  __builtin_amdgcn_global_load_lds((const __attribute__((address_space(1))) void*)g,
                                   (__attribute__((address_space(3))) void*)l, 16, 0, 0);
}

// ---------------------------------------------------------------------------
// Kernel 0: pre-split the three 128x128 weight matrices into bf16 hi/lo.
// ---------------------------------------------------------------------------
__global__ __launch_bounds__(256) void wsplit_kernel(
    const float* __restrict__ Wq, const float* __restrict__ Wk,
    const float* __restrict__ Wv, u16* __restrict__ Whi, u16* __restrict__ Wlo)
{
  const int m = blockIdx.y;
  const float* W = (m==0) ? Wq : (m==1) ? Wk : Wv;
  int i = blockIdx.x*256 + threadIdx.x;
  float f = W[i];
  u16 hb = f2bf(f);
  Whi[m*CH*CH + i] = hb;
  Wlo[m*CH*CH + i] = f2bf(f - bf2f(hb));
}

// ---------------------------------------------------------------------------
// Kernel 1: projections (one wave per 16-pixel tile), 16x16x32 MFMA.
// Q/K stored [b][i][ch] hi/lo; V stored transposed [b][c][j] hi/lo.
// ---------------------------------------------------------------------------
__global__ __launch_bounds__(64) void proj_kernel(
    const float* __restrict__ X,
    const u16* __restrict__ Whi, const u16* __restrict__ Wlo,
    const float* __restrict__ bq, const float* __restrict__ bk,
    const float* __restrict__ bv,
    u16* __restrict__ Qhi, u16* __restrict__ Qlo,
    u16* __restrict__ Khi, u16* __restrict__ Klo,
    u16* __restrict__ Vthi, u16* __restrict__ Vtlo)
{
  __shared__ float XT[16][CH+4];
  const int b = blockIdx.y, p0 = blockIdx.x*16, lane = threadIdx.x;
  #pragma unroll
  for (int h=0; h<2; ++h){
    int c = lane + h*64;
    const float* src = X + ((size_t)b*CH + c)*NP + p0;
    #pragma unroll
    for (int v4=0; v4<4; ++v4){
      f32x4 v = *(const f32x4*)(src + v4*4);
      #pragma unroll
      for (int p=0;p<4;++p) XT[v4*4+p][c] = v[p];
    }
  }
  __syncthreads();
  const int l15 = lane&15, quad = lane>>4;
  bf16x8 xh[4], xl[4];
  #pragma unroll
  for (int s=0;s<4;++s) split8(&XT[l15][s*32+quad*8], xh[s], xl[s]);

  const float* bm[2] = {bq, bk};
  u16* OH[2] = {Qhi, Khi};
  u16* OL[2] = {Qlo, Klo};
  #pragma unroll
  for (int m=0;m<2;++m){
    const u16* WH = Whi + m*CH*CH;
    const u16* WL = Wlo + m*CH*CH;
    #pragma unroll
    for (int nt=0;nt<8;++nt){
      f32x4 a = {0.f,0.f,0.f,0.f};
      #pragma unroll
      for (int s=0;s<4;++s){
        size_t g = (size_t)(nt*16+l15)*CH + s*32 + quad*8;
        bf16x8 wh = ld8(&WH[g]), wl = ld8(&WL[g]);
        a = mfma16(xh[s], wl, a);
        a = mfma16(xl[s], wh, a);
        a = mfma16(xh[s], wh, a);
      }
      int o = nt*16 + l15;
      float bias = bm[m][o];
      #pragma unroll
      for (int r=0;r<4;++r){
        int i = p0 + quad*4 + r;
        float q = a[r] + bias;
        u16 hb = f2bf(q);
        size_t idx = ((size_t)b*NP + i)*CH + o;
        OH[m][idx] = hb;
        OL[m][idx] = f2bf(q - bf2f(hb));
      }
    }
  }
  const u16* WH = Whi + 2*CH*CH;
  const u16* WL = Wlo + 2*CH*CH;
  #pragma unroll
  for (int mt=0;mt<8;++mt){
    f32x4 a = {0.f,0.f,0.f,0.f};
    #pragma unroll
    for (int s=0;s<4;++s){
      size_t g = (size_t)(mt*16+l15)*CH + s*32 + quad*8;
      bf16x8 wh = ld8(&WH[g]), wl = ld8(&WL[g]);
      a = mfma16(wh, xl[s], a);
      a = mfma16(wl, xh[s], a);
      a = mfma16(wh, xh[s], a);
    }
    #pragma unroll
    for (int r=0;r<4;++r){
      int co = mt*16 + quad*4 + r;
      float v = a[r] + bv[co];
      u16 hb = f2bf(v);
      size_t idx = ((size_t)b*CH + co)*NP + p0 + l15;
      Vthi[idx] = hb;
      Vtlo[idx] = f2bf(v - bf2f(hb));
    }
  }
}

// ---------------------------------------------------------------------------
// Kernel 2: partial column sums via S^T = K Q^T with 32x32x16 MFMA.
// K frags register-resident; Q chunks LDS-staged (dbuf). Software-pipelined:
// exp-sum of chunk n overlaps the S MFMA chain of chunk n+1.
// colpart[isplit][b][j] = sum_{i in chunk} exp(S[i][j])
// ---------------------------------------------------------------------------
__global__ __launch_bounds__(256,3) void stats_kernel(
    const u16* __restrict__ Qhi, const u16* __restrict__ Qlo,
    const u16* __restrict__ Khi, const u16* __restrict__ Klo,
    float* __restrict__ colpart)
{
  __shared__ u16 SQ[2][2][32*CH];   // [buf][hi/lo][chunk(c16)*32 + row] * 8
  const int b = blockIdx.z, isplit = blockIdx.y;
  const int tid = threadIdx.x, lane = tid&63, w = tid>>6;
  const int l31 = lane&31, h = lane>>5;
  const int j0w = blockIdx.x*128 + w*32;

  const int slot0 = w*128 + lane, slot1 = slot0 + 64;
  const int qr0 = slot0&31, qc0 = slot0>>5, qr1 = slot1&31, qc1 = slot1>>5;
  const size_t qg0 = ((size_t)b*NP + qr0)*CH + qc0*8;
  const size_t qg1 = ((size_t)b*NP + qr1)*CH + qc1*8;
  const int lof0 = slot0*8, lof1 = slot1*8;

  // K fragments register-resident: A[m=j=l31][k=ks*16+h*8+e]
  bf16x8 kh[8], kl[8];
  #pragma unroll
  for (int ks=0;ks<8;++ks){
    size_t g = ((size_t)b*NP + j0w + l31)*CH + ks*16 + h*8;
    kh[ks] = ld8(&Khi[g]);
    kl[ks] = ld8(&Klo[g]);
  }

  const int ibase = isplit*(NP/ISPL);
  const int NCH = (NP/ISPL)/32;     // 16 chunks

  auto stageQ = [&](int t){
    size_t iofs = (size_t)(ibase + t*32)*CH;
    int bf = t&1;
    gll16(&Qhi[qg0 + iofs], &SQ[bf][0][lof0]);
    gll16(&Qhi[qg1 + iofs], &SQ[bf][0][lof1]);
    gll16(&Qlo[qg0 + iofs], &SQ[bf][1][lof0]);
    gll16(&Qlo[qg1 + iofs], &SQ[bf][1][lof1]);
  };
  auto computeS = [&](int t, f32x16& s){
    const u16* Qh = &SQ[t&1][0][0];
    const u16* Ql = &SQ[t&1][1][0];
    #pragma unroll
    for (int r=0;r<16;++r) s[r] = 0.f;
    #pragma unroll
    for (int ks=0;ks<8;++ks){
      int o = (ks*2+h)*256 + l31*8;      // B[k][n=i=l31]
      bf16x8 qbh = ld8(&Qh[o]);
      bf16x8 qbl = ld8(&Ql[o]);
      s = mfma32(kh[ks], qbl, s);
      s = mfma32(kl[ks], qbh, s);
      s = mfma32(kh[ks], qbh, s);
    }
  };

  stageQ(0); stageQ(1);
  __syncthreads();                  // chunks 0,1 staged
  f32x16 s;
  computeS(0, s);
  __syncthreads();                  // all waves done reading SQ[0]

  float scol[16];
  #pragma unroll
  for (int r=0;r<16;++r) scol[r] = 0.f;

  for (int ic=0; ic<NCH; ++ic){
    if (ic+2 < NCH) stageQ(ic+2);   // -> SQ[ic&1], safe after prev barrier
    #pragma unroll
    for (int r=0;r<16;++r) scol[r] += __expf(s[r]);
    if (ic+1 < NCH) computeS(ic+1, s); // reads SQ[(ic+1)&1], staged+drained
    __syncthreads();
  }
  // reduce over the 32 i-lanes (same h keeps same j)
  #pragma unroll
  for (int m=1; m<32; m<<=1){
    #pragma unroll
    for (int r=0;r<16;++r) scol[r] += __shfl_xor(scol[r], m);
  }
  if (l31 == 0){
    #pragma unroll
    for (int r=0;r<16;++r){
      int j = j0w + (r&3) + 8*(r>>2) + 4*h;
      colpart[((size_t)(isplit*NB + b))*NP + j] = scol[r];
    }
  }
}

// ---------------------------------------------------------------------------
// Kernel 3: in-place V' = rinv_j * V (hi/lo re-split), rinv computed inline
// from the ISPL colpart partials.
// ---------------------------------------------------------------------------
__global__ __launch_bounds__(256) void scalev_kernel(
    u16* __restrict__ Vthi, u16* __restrict__ Vtlo,
    const float* __restrict__ colpart)
{
  size_t t = (size_t)blockIdx.x*256 + threadIdx.x;
  size_t base = t*8;
  int bc = (int)(base >> 12);
  int b  = bc >> 7;
  int j0 = (int)(base & (NP-1));
  f32x4 s0 = {0.f,0.f,0.f,0.f}, s1 = {0.f,0.f,0.f,0.f};
  #pragma unroll
  for (int k=0;k<ISPL;++k){
    const float* cp = &colpart[((size_t)(k*NB + b))*NP + j0];
    f32x4 a0 = *(const f32x4*)cp;
    f32x4 a1 = *(const f32x4*)(cp+4);
    #pragma unroll
    for (int e=0;e<4;++e){ s0[e]+=a0[e]; s1[e]+=a1[e]; }
  }
  us8 hh = *(const us8*)&Vthi[base];
  us8 ll = *(const us8*)&Vtlo[base];
  us8 oh, ol;
  #pragma unroll
  for (int e=0;e<8;++e){
    float r = 1.0f / (e<4 ? s0[e] : s1[e-4]);
    float v = (bf2f(hh[e]) + bf2f(ll[e])) * r;
    u16 hb = f2bf(v);
    oh[e] = hb;
    ol[e] = f2bf(v - bf2f(hb));
  }
  *(us8*)&Vthi[base] = oh;
  *(us8*)&Vtlo[base] = ol;
}

// ---------------------------------------------------------------------------
// Kernel 4: flash attn, 32x32x16, S^T formulation, in-register P transpose.
// Software-pipelined: S(jt+1) MFMAs overlap exp/pack/PV(jt). K staged 2
// ahead, V 1 ahead, ONE barrier per j-tile (staging issued at iteration top
// so the barrier's vmcnt drain hides under ~800 cyc of compute).
// ---------------------------------------------------------------------------
__global__ __launch_bounds__(256,2) void attn_kernel(
    const u16* __restrict__ Qhi, const u16* __restrict__ Qlo,
    const u16* __restrict__ Khi, const u16* __restrict__ Klo,
    const u16* __restrict__ Vthi, const u16* __restrict__ Vtlo,
    float* __restrict__ xacc)
{
  __shared__ u16 SK[2][2][32*CH];    // [buf][hi/lo][chunk(c16)*32 + row] * 8
  __shared__ u16 SV[2][2][4*CH*8];   // [buf][hi/lo][chunk(c4)*128 + row] * 8
  const int b = blockIdx.z, jsplit = blockIdx.y;
  const int tid = threadIdx.x, lane = tid&63, w = tid>>6;
  const int l31 = lane&31, h = lane>>5;
  const int i0w = blockIdx.x*128 + w*32;
  const bool hb1 = (h != 0);

  // staging: 512 slots of 16B per array-half, 2 per thread
  const int slot0 = tid, slot1 = tid + 256;
  const int kr0 = slot0&31, kc0 = slot0>>5, kr1 = slot1&31, kc1 = slot1>>5;
  const int vr0 = slot0&127, vc0 = slot0>>7, vr1 = slot1&127, vc1 = slot1>>7;
  const size_t kg0 = ((size_t)b*NP + kr0)*CH + kc0*8;
  const size_t kg1 = ((size_t)b*NP + kr1)*CH + kc1*8;
  const size_t vg0 = ((size_t)b*CH + vr0)*NP + vc0*8;
  const size_t vg1 = ((size_t)b*CH + vr1)*NP + vc1*8;
  const int lof0 = slot0*8, lof1 = slot1*8;

  const int jbase = jsplit*(NP/JSPL);
  const int NJT = (NP/JSPL)/32;      // 32 j-tiles

  auto stageK = [&](int t){
    size_t jofs = (size_t)(jbase + t*32)*CH;
    int bf = t&1;
    gll16(&Khi[kg0 + jofs], &SK[bf][0][lof0]);
    gll16(&Khi[kg1 + jofs], &SK[bf][0][lof1]);
    gll16(&Klo[kg0 + jofs], &SK[bf][1][lof0]);
    gll16(&Klo[kg1 + jofs], &SK[bf][1][lof1]);
  };
  auto stageV = [&](int t){
    int j0 = jbase + t*32;
    int bf = t&1;
    gll16(&Vthi[vg0 + j0], &SV[bf][0][lof0]);
    gll16(&Vthi[vg1 + j0], &SV[bf][0][lof1]);
    gll16(&Vtlo[vg0 + j0], &SV[bf][1][lof0]);
    gll16(&Vtlo[vg1 + j0], &SV[bf][1][lof1]);
  };

  // Q B-fragments resident: B[k=ks*16+h*8+e][n=i=l31]
  bf16x8 qh[8], ql[8];
  #pragma unroll
  for (int ks=0;ks<8;++ks){
    size_t g = ((size_t)b*NP + i0w + l31)*CH + ks*16 + h*8;
    qh[ks] = ld8(&Qhi[g]); ql[ks] = ld8(&Qlo[g]);
  }

  auto computeS = [&](int t, f32x16& s){
    const u16* Kh = &SK[t&1][0][0];
    const u16* Kl = &SK[t&1][1][0];
    #pragma unroll
    for (int r=0;r<16;++r) s[r] = 0.f;
    #pragma unroll
    for (int ks=0;ks<8;++ks){
      int o = (ks*2+h)*256 + l31*8;
      bf16x8 ah = ld8(&Kh[o]);
      bf16x8 al = ld8(&Kl[o]);
      s = mfma32(ah, ql[ks], s);
      s = mfma32(al, qh[ks], s);
      s = mfma32(ah, qh[ks], s);
    }
  };

  f32x16 acc[4];
  #pragma unroll
  for (int mt=0;mt<4;++mt)
    #pragma unroll
    for (int r=0;r<16;++r) acc[mt][r] = 0.f;

  // prologue: tile0 (K+V) and tile1 (K) staged; S(0) computed
  stageK(0); stageV(0); stageK(1);
  __syncthreads();                   // tiles staged (vmcnt drained)
  f32x16 s;
  computeS(0, s);
  __syncthreads();                   // all waves done reading SK[0]

  for (int jt=0; jt<NJT; ++jt){
    const int cb = jt&1;
    if (jt+2 < NJT) stageK(jt+2);    // -> SK[cb]   (K(jt) reads done)
    if (jt+1 < NJT) stageV(jt+1);    // -> SV[cb^1] (V(jt-1) reads done)

    float p[16];
    #pragma unroll
    for (int r=0;r<16;++r) p[r] = __expf(s[r]);

    if (jt+1 < NJT) computeS(jt+1, s);   // reads SK[cb^1], staged+drained

    const u16* Vh = &SV[cb][0][0];
    const u16* Vl = &SV[cb][1][0];
    // two k-tiles of 16 j each: assemble P^T B-frags in-register
    #pragma unroll
    for (int t=0;t<2;++t){
      unsigned hA,lA,hB,lB,hC,lC,hD,lD;
      pksplit(p[8*t+0], p[8*t+1], hA, lA);
      pksplit(p[8*t+2], p[8*t+3], hB, lB);
      pksplit(p[8*t+4], p[8*t+5], hC, lC);
      pksplit(p[8*t+6], p[8*t+7], hD, lD);
      unsigned s0h = hb1? hA:hC, s1h = hb1? hB:hD;
      unsigned s0l = hb1? lA:lC, s1l = hb1? lB:lD;
      unsigned r0h = __shfl_xor(s0h, 32), r1h = __shfl_xor(s1h, 32);
      unsigned r0l = __shfl_xor(s0l, 32), r1l = __shfl_xor(s1l, 32);
      unsigned dh[4], dl[4];
      dh[0] = hb1? r0h : hA;  dh[1] = hb1? r1h : hB;
      dh[2] = hb1? hC  : r0h; dh[3] = hb1? hD  : r1h;
      dl[0] = hb1? r0l : lA;  dl[1] = hb1? r1l : lB;
      dl[2] = hb1? lC  : r0l; dl[3] = hb1? lD  : r1l;
      bf16x8 Bh, Bl;
      __builtin_memcpy(&Bh, dh, 16);
      __builtin_memcpy(&Bl, dl, 16);
      // PV: A = V'^T[m=c][k=j], B = P^T -> acc[c][i]
      #pragma unroll
      for (int mt=0;mt<4;++mt){
        int o = (t*2+h)*1024 + (mt*32+l31)*8;
        bf16x8 vh = ld8(&Vh[o]);
        bf16x8 vl = ld8(&Vl[o]);
        acc[mt] = mfma32(vh, Bl, acc[mt]);
        acc[mt] = mfma32(vl, Bh, acc[mt]);
        acc[mt] = mfma32(vh, Bh, acc[mt]);
      }
    }
    __syncthreads();                 // buf free + next staging drained
  }
  // epilogue: acc[mt][r] = O^T[c][i], c = mt*32+(r&3)+8*(r>>2)+4*h, i = i0w+l31
  float* xp = xacc + (size_t)b*CH*NP;
  #pragma unroll
  for (int mt=0;mt<4;++mt){
    #pragma unroll
    for (int r=0;r<16;++r){
      int c = mt*32 + (r&3) + 8*(r>>2) + 4*h;
      atomicAdd(&xp[(size_t)c*NP + i0w + l31], acc[mt][r]);
    }
  }
}

// ---------------------------------------------------------------------------
// Kernel 5: out = X + xacc
// ---------------------------------------------------------------------------
__global__ __launch_bounds__(256) void final_kernel(
    const float* __restrict__ X, const float* __restrict__ xacc,
    float* __restrict__ out)
{
  size_t idx = ((size_t)blockIdx.x*256 + threadIdx.x)*4;
  f32x4 x = *(const f32x4*)&X[idx];
  f32x4 a = *(const f32x4*)&xacc[idx];
  f32x4 r;
  #pragma unroll
  for (int e=0;e<4;++e) r[e] = x[e] + a[e];
  *(f32x4*)&out[idx] = r;
}

extern "C" void kernel_launch(void* const* d_in, const int* in_sizes, int n_in,
                              void* d_out, int out_size, void* d_ws, size_t ws_size,
                              hipStream_t stream)
{
  const float* X  = (const float*)d_in[0];
  const float* Wq = (const float*)d_in[1];
  const float* bq = (const float*)d_in[2];
  const float* Wk = (const float*)d_in[3];
  const float* bk = (const float*)d_in[4];
  const float* Wv = (const float*)d_in[5];
  const float* bv = (const float*)d_in[6];
  float* outp = (float*)d_out;

  const size_t n = (size_t)NB*NP*CH;        // 2,097,152
  u16* Qhi = (u16*)d_ws;
  u16* Qlo = Qhi + n;
  u16* Khi = Qlo + n;
  u16* Klo = Khi + n;
  u16* Vthi = Klo + n;
  u16* Vtlo = Vthi + n;
  u16* Whi  = Vtlo + n;
  u16* Wlo  = Whi + 3*CH*CH;
  float* colpart = (float*)(Wlo + 3*CH*CH);      // ISPL*NB*NP
  float* xacc    = colpart + (size_t)ISPL*NB*NP; // NB*CH*NP fp32 = 8 MB

  hipMemsetAsync(xacc, 0, n*sizeof(float), stream);

  wsplit_kernel<<<dim3(CH*CH/256, 3),      256, 0, stream>>>(Wq, Wk, Wv, Whi, Wlo);
  proj_kernel  <<<dim3(NP/16, NB),          64, 0, stream>>>(X, Whi, Wlo, bq, bk, bv,
                                                             Qhi,Qlo, Khi,Klo, Vthi,Vtlo);
  stats_kernel <<<dim3(NP/128, ISPL, NB),  256, 0, stream>>>(Qhi,Qlo, Khi,Klo, colpart);
  scalev_kernel<<<dim3(n/(256*8)),         256, 0, stream>>>(Vthi, Vtlo, colpart);
  attn_kernel  <<<dim3(NP/128, JSPL, NB),  256, 0, stream>>>(Qhi,Qlo, Khi,Klo,
                                                             Vthi,Vtlo, xacc);
  final_kernel <<<dim3(n/(256*4)),         256, 0, stream>>>(X, xacc, outp);
}

// Round 9
// 282.987 us; speedup vs baseline: 1.3445x; 1.0025x over previous
//
#include <hip/hip_runtime.h>
#include <hip/hip_bf16.h>

// SelfAttention (B=4, C=128, H=W=64), fp32 I/O.
// out[b,c,i] = X[b,c,i] + sum_j exp(S[i,j]) * rinv_j * V[j,c],
//   S = Q K^T, rinv_j = 1/sum_i exp(S[i,j])   (softmax over query axis)
// fp32-faithful via split-bf16 (hi+lo) 3-term MFMA emulation, 32x32x16 MFMA.
// attn/stats software-pipelined; co-resident block pairs start-staggered
// (s_sleep) to anti-phase their MFMA/VALU/LDS phases on shared SIMDs.

typedef unsigned short u16;
typedef __attribute__((ext_vector_type(8))) __bf16 bf16x8;
typedef __attribute__((ext_vector_type(8))) unsigned short us8;
typedef __attribute__((ext_vector_type(4))) float f32x4;
typedef __attribute__((ext_vector_type(16))) float f32x16;

#define NB 4
#define CH 128
#define NP 4096
#define JSPL 4   // attn j-splits (partials into xacc)
#define ISPL 8   // stats i-splits (partials into colpart)

__device__ __forceinline__ float bf2f(u16 b){ union{float f;unsigned u;}v; v.u=((unsigned)b)<<16; return v.f; }
__device__ __forceinline__ u16 f2bf(float f){ union{float f;unsigned u;}v; v.f=f; unsigned r=v.u + 0x7FFFu + ((v.u>>16)&1u); return (u16)(r>>16); }

__device__ __forceinline__ f32x4 mfma16(bf16x8 a, bf16x8 b, f32x4 c){
  return __builtin_amdgcn_mfma_f32_16x16x32_bf16(a, b, c, 0, 0, 0);
}
__device__ __forceinline__ f32x16 mfma32(bf16x8 a, bf16x8 b, f32x16 c){
  return __builtin_amdgcn_mfma_f32_32x32x16_bf16(a, b, c, 0, 0, 0);
}
__device__ __forceinline__ bf16x8 ld8(const u16* p){
  union { us8 u; bf16x8 b; } v; v.u = *(const us8*)p; return v.b;
}
__device__ __forceinline__ void split8(const float* p, bf16x8& h, bf16x8& l){
  union { us8 u; bf16x8 b; } uh, ul;
  #pragma unroll
  for (int e=0;e<8;++e){
    float f = p[e];
    u16 hb = f2bf(f);
    uh.u[e] = hb;
    ul.u[e] = f2bf(f - bf2f(hb));
  }
  h = uh.b; l = ul.b;
}
// pack (a,b) -> bf16 pair dword (hi) + residual bf16 pair dword (lo), RNE
__device__ __forceinline__ void pksplit(float a, float b, unsigned& dhi, unsigned& dlo){
  float2 f2; f2.x = a; f2.y = b;
  __hip_bfloat162 hb = __float22bfloat162_rn(f2);
  unsigned u; __builtin_memcpy(&u, &hb, 4);
  dhi = u;
  union{unsigned x;float f;} ca, cb;
  ca.x = u << 16; cb.x = u & 0xFFFF0000u;
  float2 g2; g2.x = a - ca.f; g2.y = b - cb.f;
  __hip_bfloat162 lb = __float22bfloat162_rn(g2);
  __builtin_memcpy(&dlo, &lb, 4);
}
__device__ __forceinline__ void gll16(const void* g, void* l){
  __builtin_amdgcn_global_load_lds((const __attribute__((address_space(1))) void*)g,
                                   (__attribute__((address_space(3))) void*)l, 16, 0, 0);
}
// one-time start stagger: ~640 cycles (10 * 64-cyc sleep quanta)
__device__ __forceinline__ void stagger(int on){
  if (on){ __builtin_amdgcn_s_sleep(10); }
}

// ---------------------------------------------------------------------------
// Kernel 0: pre-split the three 128x128 weight matrices into bf16 hi/lo.
// ---------------------------------------------------------------------------
__global__ __launch_bounds__(256) void wsplit_kernel(
    const float* __restrict__ Wq, const float* __restrict__ Wk,
    const float* __restrict__ Wv, u16* __restrict__ Whi, u16* __restrict__ Wlo)
{
  const int m = blockIdx.y;
  const float* W = (m==0) ? Wq : (m==1) ? Wk : Wv;
  int i = blockIdx.x*256 + threadIdx.x;
  float f = W[i];
  u16 hb = f2bf(f);
  Whi[m*CH*CH + i] = hb;
  Wlo[m*CH*CH + i] = f2bf(f - bf2f(hb));
}

// ---------------------------------------------------------------------------
// Kernel 1: projections (one wave per 16-pixel tile), 16x16x32 MFMA.
// Q/K stored [b][i][ch] hi/lo; V stored transposed [b][c][j] hi/lo.
// ---------------------------------------------------------------------------
__global__ __launch_bounds__(64) void proj_kernel(
    const float* __restrict__ X,
    const u16* __restrict__ Whi, const u16* __restrict__ Wlo,
    const float* __restrict__ bq, const float* __restrict__ bk,
    const float* __restrict__ bv,
    u16* __restrict__ Qhi, u16* __restrict__ Qlo,
    u16* __restrict__ Khi, u16* __restrict__ Klo,
    u16* __restrict__ Vthi, u16* __restrict__ Vtlo)
{
  __shared__ float XT[16][CH+4];
  const int b = blockIdx.y, p0 = blockIdx.x*16, lane = threadIdx.x;
  #pragma unroll
  for (int h=0; h<2; ++h){
    int c = lane + h*64;
    const float* src = X + ((size_t)b*CH + c)*NP + p0;
    #pragma unroll
    for (int v4=0; v4<4; ++v4){
      f32x4 v = *(const f32x4*)(src + v4*4);
      #pragma unroll
      for (int p=0;p<4;++p) XT[v4*4+p][c] = v[p];
    }
  }
  __syncthreads();
  const int l15 = lane&15, quad = lane>>4;
  bf16x8 xh[4], xl[4];
  #pragma unroll
  for (int s=0;s<4;++s) split8(&XT[l15][s*32+quad*8], xh[s], xl[s]);

  const float* bm[2] = {bq, bk};
  u16* OH[2] = {Qhi, Khi};
  u16* OL[2] = {Qlo, Klo};
  #pragma unroll
  for (int m=0;m<2;++m){
    const u16* WH = Whi + m*CH*CH;
    const u16* WL = Wlo + m*CH*CH;
    #pragma unroll
    for (int nt=0;nt<8;++nt){
      f32x4 a = {0.f,0.f,0.f,0.f};
      #pragma unroll
      for (int s=0;s<4;++s){
        size_t g = (size_t)(nt*16+l15)*CH + s*32 + quad*8;
        bf16x8 wh = ld8(&WH[g]), wl = ld8(&WL[g]);
        a = mfma16(xh[s], wl, a);
        a = mfma16(xl[s], wh, a);
        a = mfma16(xh[s], wh, a);
      }
      int o = nt*16 + l15;
      float bias = bm[m][o];
      #pragma unroll
      for (int r=0;r<4;++r){
        int i = p0 + quad*4 + r;
        float q = a[r] + bias;
        u16 hb = f2bf(q);
        size_t idx = ((size_t)b*NP + i)*CH + o;
        OH[m][idx] = hb;
        OL[m][idx] = f2bf(q - bf2f(hb));
      }
    }
  }
  const u16* WH = Whi + 2*CH*CH;
  const u16* WL = Wlo + 2*CH*CH;
  #pragma unroll
  for (int mt=0;mt<8;++mt){
    f32x4 a = {0.f,0.f,0.f,0.f};
    #pragma unroll
    for (int s=0;s<4;++s){
      size_t g = (size_t)(mt*16+l15)*CH + s*32 + quad*8;
      bf16x8 wh = ld8(&WH[g]), wl = ld8(&WL[g]);
      a = mfma16(wh, xl[s], a);
      a = mfma16(wl, xh[s], a);
      a = mfma16(wh, xh[s], a);
    }
    #pragma unroll
    for (int r=0;r<4;++r){
      int co = mt*16 + quad*4 + r;
      float v = a[r] + bv[co];
      u16 hb = f2bf(v);
      size_t idx = ((size_t)b*CH + co)*NP + p0 + l15;
      Vthi[idx] = hb;
      Vtlo[idx] = f2bf(v - bf2f(hb));
    }
  }
}

// ---------------------------------------------------------------------------
// Kernel 2: partial column sums via S^T = K Q^T with 32x32x16 MFMA.
// K frags register-resident; Q chunks LDS-staged (dbuf). Software-pipelined:
// exp-sum of chunk n overlaps the S MFMA chain of chunk n+1.
// colpart[isplit][b][j] = sum_{i in chunk} exp(S[i][j])
// ---------------------------------------------------------------------------
__global__ __launch_bounds__(256,3) void stats_kernel(
    const u16* __restrict__ Qhi, const u16* __restrict__ Qlo,
    const u16* __restrict__ Khi, const u16* __restrict__ Klo,
    float* __restrict__ colpart)
{
  __shared__ u16 SQ[2][2][32*CH];   // [buf][hi/lo][chunk(c16)*32 + row] * 8
  const int b = blockIdx.z, isplit = blockIdx.y;
  const int tid = threadIdx.x, lane = tid&63, w = tid>>6;
  const int l31 = lane&31, h = lane>>5;
  const int j0w = blockIdx.x*128 + w*32;

  // co-resident pairs differ by 256 in linear id = bit0 of z -> anti-phase
  stagger(blockIdx.z & 1);

  const int slot0 = w*128 + lane, slot1 = slot0 + 64;
  const int qr0 = slot0&31, qc0 = slot0>>5, qr1 = slot1&31, qc1 = slot1>>5;
  const size_t qg0 = ((size_t)b*NP + qr0)*CH + qc0*8;
  const size_t qg1 = ((size_t)b*NP + qr1)*CH + qc1*8;
  const int lof0 = slot0*8, lof1 = slot1*8;

  // K fragments register-resident: A[m=j=l31][k=ks*16+h*8+e]
  bf16x8 kh[8], kl[8];
  #pragma unroll
  for (int ks=0;ks<8;++ks){
    size_t g = ((size_t)b*NP + j0w + l31)*CH + ks*16 + h*8;
    kh[ks] = ld8(&Khi[g]);
    kl[ks] = ld8(&Klo[g]);
  }

  const int ibase = isplit*(NP/ISPL);
  const int NCH = (NP/ISPL)/32;     // 16 chunks

  auto stageQ = [&](int t){
    size_t iofs = (size_t)(ibase + t*32)*CH;
    int bf = t&1;
    gll16(&Qhi[qg0 + iofs], &SQ[bf][0][lof0]);
    gll16(&Qhi[qg1 + iofs], &SQ[bf][0][lof1]);
    gll16(&Qlo[qg0 + iofs], &SQ[bf][1][lof0]);
    gll16(&Qlo[qg1 + iofs], &SQ[bf][1][lof1]);
  };
  auto computeS = [&](int t, f32x16& s){
    const u16* Qh = &SQ[t&1][0][0];
    const u16* Ql = &SQ[t&1][1][0];
    #pragma unroll
    for (int r=0;r<16;++r) s[r] = 0.f;
    #pragma unroll
    for (int ks=0;ks<8;++ks){
      int o = (ks*2+h)*256 + l31*8;      // B[k][n=i=l31]
      bf16x8 qbh = ld8(&Qh[o]);
      bf16x8 qbl = ld8(&Ql[o]);
      s = mfma32(kh[ks], qbl, s);
      s = mfma32(kl[ks], qbh, s);
      s = mfma32(kh[ks], qbh, s);
    }
  };

  stageQ(0); stageQ(1);
  __syncthreads();                  // chunks 0,1 staged
  f32x16 s;
  computeS(0, s);
  __syncthreads();                  // all waves done reading SQ[0]

  float scol[16];
  #pragma unroll
  for (int r=0;r<16;++r) scol[r] = 0.f;

  for (int ic=0; ic<NCH; ++ic){
    if (ic+2 < NCH) stageQ(ic+2);   // -> SQ[ic&1], safe after prev barrier
    #pragma unroll
    for (int r=0;r<16;++r) scol[r] += __expf(s[r]);
    if (ic+1 < NCH) computeS(ic+1, s); // reads SQ[(ic+1)&1], staged+drained
    __syncthreads();
  }
  // reduce over the 32 i-lanes (same h keeps same j)
  #pragma unroll
  for (int m=1; m<32; m<<=1){
    #pragma unroll
    for (int r=0;r<16;++r) scol[r] += __shfl_xor(scol[r], m);
  }
  if (l31 == 0){
    #pragma unroll
    for (int r=0;r<16;++r){
      int j = j0w + (r&3) + 8*(r>>2) + 4*h;
      colpart[((size_t)(isplit*NB + b))*NP + j] = scol[r];
    }
  }
}

// ---------------------------------------------------------------------------
// Kernel 3: in-place V' = rinv_j * V (hi/lo re-split), rinv computed inline
// from the ISPL colpart partials.
// ---------------------------------------------------------------------------
__global__ __launch_bounds__(256) void scalev_kernel(
    u16* __restrict__ Vthi, u16* __restrict__ Vtlo,
    const float* __restrict__ colpart)
{
  size_t t = (size_t)blockIdx.x*256 + threadIdx.x;
  size_t base = t*8;
  int bc = (int)(base >> 12);
  int b  = bc >> 7;
  int j0 = (int)(base & (NP-1));
  f32x4 s0 = {0.f,0.f,0.f,0.f}, s1 = {0.f,0.f,0.f,0.f};
  #pragma unroll
  for (int k=0;k<ISPL;++k){
    const float* cp = &colpart[((size_t)(k*NB + b))*NP + j0];
    f32x4 a0 = *(const f32x4*)cp;
    f32x4 a1 = *(const f32x4*)(cp+4);
    #pragma unroll
    for (int e=0;e<4;++e){ s0[e]+=a0[e]; s1[e]+=a1[e]; }
  }
  us8 hh = *(const us8*)&Vthi[base];
  us8 ll = *(const us8*)&Vtlo[base];
  us8 oh, ol;
  #pragma unroll
  for (int e=0;e<8;++e){
    float r = 1.0f / (e<4 ? s0[e] : s1[e-4]);
    float v = (bf2f(hh[e]) + bf2f(ll[e])) * r;
    u16 hb = f2bf(v);
    oh[e] = hb;
    ol[e] = f2bf(v - bf2f(hb));
  }
  *(us8*)&Vthi[base] = oh;
  *(us8*)&Vtlo[base] = ol;
}

// ---------------------------------------------------------------------------
// Kernel 4: flash attn, 32x32x16, S^T formulation, in-register P transpose.
// Software-pipelined: S(jt+1) MFMAs overlap exp/pack/PV(jt). K staged 2
// ahead, V 1 ahead, ONE barrier per j-tile. Co-resident block pairs
// (linear ids n, n+256 -> z differs by 2) are start-staggered.
// ---------------------------------------------------------------------------
__global__ __launch_bounds__(256,2) void attn_kernel(
    const u16* __restrict__ Qhi, const u16* __restrict__ Qlo,
    const u16* __restrict__ Khi, const u16* __restrict__ Klo,
    const u16* __restrict__ Vthi, const u16* __restrict__ Vtlo,
    float* __restrict__ xacc)
{
  __shared__ u16 SK[2][2][32*CH];    // [buf][hi/lo][chunk(c16)*32 + row] * 8
  __shared__ u16 SV[2][2][4*CH*8];   // [buf][hi/lo][chunk(c4)*128 + row] * 8
  const int b = blockIdx.z, jsplit = blockIdx.y;
  const int tid = threadIdx.x, lane = tid&63, w = tid>>6;
  const int l31 = lane&31, h = lane>>5;
  const int i0w = blockIdx.x*128 + w*32;
  const bool hb1 = (h != 0);

  // grid (32,4,4): linear = x+32y+128z; bit 8 flips between n and n+256
  stagger((blockIdx.z >> 1) & 1);

  // staging: 512 slots of 16B per array-half, 2 per thread
  const int slot0 = tid, slot1 = tid + 256;
  const int kr0 = slot0&31, kc0 = slot0>>5, kr1 = slot1&31, kc1 = slot1>>5;
  const int vr0 = slot0&127, vc0 = slot0>>7, vr1 = slot1&127, vc1 = slot1>>7;
  const size_t kg0 = ((size_t)b*NP + kr0)*CH + kc0*8;
  const size_t kg1 = ((size_t)b*NP + kr1)*CH + kc1*8;
  const size_t vg0 = ((size_t)b*CH + vr0)*NP + vc0*8;
  const size_t vg1 = ((size_t)b*CH + vr1)*NP + vc1*8;
  const int lof0 = slot0*8, lof1 = slot1*8;

  const int jbase = jsplit*(NP/JSPL);
  const int NJT = (NP/JSPL)/32;      // 32 j-tiles

  auto stageK = [&](int t){
    size_t jofs = (size_t)(jbase + t*32)*CH;
    int bf = t&1;
    gll16(&Khi[kg0 + jofs], &SK[bf][0][lof0]);
    gll16(&Khi[kg1 + jofs], &SK[bf][0][lof1]);
    gll16(&Klo[kg0 + jofs], &SK[bf][1][lof0]);
    gll16(&Klo[kg1 + jofs], &SK[bf][1][lof1]);
  };
  auto stageV = [&](int t){
    int j0 = jbase + t*32;
    int bf = t&1;
    gll16(&Vthi[vg0 + j0], &SV[bf][0][lof0]);
    gll16(&Vthi[vg1 + j0], &SV[bf][0][lof1]);
    gll16(&Vtlo[vg0 + j0], &SV[bf][1][lof0]);
    gll16(&Vtlo[vg1 + j0], &SV[bf][1][lof1]);
  };

  // Q B-fragments resident: B[k=ks*16+h*8+e][n=i=l31]
  bf16x8 qh[8], ql[8];
  #pragma unroll
  for (int ks=0;ks<8;++ks){
    size_t g = ((size_t)b*NP + i0w + l31)*CH + ks*16 + h*8;
    qh[ks] = ld8(&Qhi[g]); ql[ks] = ld8(&Qlo[g]);
  }

  auto computeS = [&](int t, f32x16& s){
    const u16* Kh = &SK[t&1][0][0];
    const u16* Kl = &SK[t&1][1][0];
    #pragma unroll
    for (int r=0;r<16;++r) s[r] = 0.f;
    #pragma unroll
    for (int ks=0;ks<8;++ks){
      int o = (ks*2+h)*256 + l31*8;
      bf16x8 ah = ld8(&Kh[o]);
      bf16x8 al = ld8(&Kl[o]);
      s = mfma32(ah, ql[ks], s);
      s = mfma32(al, qh[ks], s);
      s = mfma32(ah, qh[ks], s);
    }
  };

  f32x16 acc[4];
  #pragma unroll
  for (int mt=0;mt<4;++mt)
    #pragma unroll
    for (int r=0;r<16;++r) acc[mt][r] = 0.f;

  // prologue: tile0 (K+V) and tile1 (K) staged; S(0) computed
  stageK(0); stageV(0); stageK(1);
  __syncthreads();                   // tiles staged (vmcnt drained)
  f32x16 s;
  computeS(0, s);
  __syncthreads();                   // all waves done reading SK[0]

  for (int jt=0; jt<NJT; ++jt){
    const int cb = jt&1;
    if (jt+2 < NJT) stageK(jt+2);    // -> SK[cb]   (K(jt) reads done)
    if (jt+1 < NJT) stageV(jt+1);    // -> SV[cb^1] (V(jt-1) reads done)

    float p[16];
    #pragma unroll
    for (int r=0;r<16;++r) p[r] = __expf(s[r]);

    if (jt+1 < NJT) computeS(jt+1, s);   // reads SK[cb^1], staged+drained

    const u16* Vh = &SV[cb][0][0];
    const u16* Vl = &SV[cb][1][0];
    // two k-tiles of 16 j each: assemble P^T B-frags in-register
    #pragma unroll
    for (int t=0;t<2;++t){
      unsigned hA,lA,hB,lB,hC,lC,hD,lD;
      pksplit(p[8*t+0], p[8*t+1], hA, lA);
      pksplit(p[8*t+2], p[8*t+3], hB, lB);
      pksplit(p[8*t+4], p[8*t+5], hC, lC);
      pksplit(p[8*t+6], p[8*t+7], hD, lD);
      unsigned s0h = hb1? hA:hC, s1h = hb1? hB:hD;
      unsigned s0l = hb1? lA:lC, s1l = hb1? lB:lD;
      unsigned r0h = __shfl_xor(s0h, 32), r1h = __shfl_xor(s1h, 32);
      unsigned r0l = __shfl_xor(s0l, 32), r1l = __shfl_xor(s1l, 32);
      unsigned dh[4], dl[4];
      dh[0] = hb1? r0h : hA;  dh[1] = hb1? r1h : hB;
      dh[2] = hb1? hC  : r0h; dh[3] = hb1? hD  : r1h;
      dl[0] = hb1? r0l : lA;  dl[1] = hb1? r1l : lB;
      dl[2] = hb1? lC  : r0l; dl[3] = hb1? lD  : r1l;
      bf16x8 Bh, Bl;
      __builtin_memcpy(&Bh, dh, 16);
      __builtin_memcpy(&Bl, dl, 16);
      // PV: A = V'^T[m=c][k=j], B = P^T -> acc[c][i]
      #pragma unroll
      for (int mt=0;mt<4;++mt){
        int o = (t*2+h)*1024 + (mt*32+l31)*8;
        bf16x8 vh = ld8(&Vh[o]);
        bf16x8 vl = ld8(&Vl[o]);
        acc[mt] = mfma32(vh, Bl, acc[mt]);
        acc[mt] = mfma32(vl, Bh, acc[mt]);
        acc[mt] = mfma32(vh, Bh, acc[mt]);
      }
    }
    __syncthreads();                 // buf free + next staging drained
  }
  // epilogue: acc[mt][r] = O^T[c][i], c = mt*32+(r&3)+8*(r>>2)+4*h, i = i0w+l31
  float* xp = xacc + (size_t)b*CH*NP;
  #pragma unroll
  for (int mt=0;mt<4;++mt){
    #pragma unroll
    for (int r=0;r<16;++r){
      int c = mt*32 + (r&3) + 8*(r>>2) + 4*h;
      atomicAdd(&xp[(size_t)c*NP + i0w + l31], acc[mt][r]);
    }
  }
}

// ---------------------------------------------------------------------------
// Kernel 5: out = X + xacc
// ---------------------------------------------------------------------------
__global__ __launch_bounds__(256) void final_kernel(
    const float* __restrict__ X, const float* __restrict__ xacc,
    float* __restrict__ out)
{
  size_t idx = ((size_t)blockIdx.x*256 + threadIdx.x)*4;
  f32x4 x = *(const f32x4*)&X[idx];
  f32x4 a = *(const f32x4*)&xacc[idx];
  f32x4 r;
  #pragma unroll
  for (int e=0;e<4;++e) r[e] = x[e] + a[e];
  *(f32x4*)&out[idx] = r;
}

extern "C" void kernel_launch(void* const* d_in, const int* in_sizes, int n_in,
                              void* d_out, int out_size, void* d_ws, size_t ws_size,
                              hipStream_t stream)
{
  const float* X  = (const float*)d_in[0];
  const float* Wq = (const float*)d_in[1];
  const float* bq = (const float*)d_in[2];
  const float* Wk = (const float*)d_in[3];
  const float* bk = (const float*)d_in[4];
  const float* Wv = (const float*)d_in[5];
  const float* bv = (const float*)d_in[6];
  float* outp = (float*)d_out;

  const size_t n = (size_t)NB*NP*CH;        // 2,097,152
  u16* Qhi = (u16*)d_ws;
  u16* Qlo = Qhi + n;
  u16* Khi = Qlo + n;
  u16* Klo = Khi + n;
  u16* Vthi = Klo + n;
  u16* Vtlo = Vthi + n;
  u16* Whi  = Vtlo + n;
  u16* Wlo  = Whi + 3*CH*CH;
  float* colpart = (float*)(Wlo + 3*CH*CH);      // ISPL*NB*NP
  float* xacc    = colpart + (size_t)ISPL*NB*NP; // NB*CH*NP fp32 = 8 MB

  hipMemsetAsync(xacc, 0, n*sizeof(float), stream);

  wsplit_kernel<<<dim3(CH*CH/256, 3),      256, 0, stream>>>(Wq, Wk, Wv, Whi, Wlo);
  proj_kernel  <<<dim3(NP/16, NB),          64, 0, stream>>>(X, Whi, Wlo, bq, bk, bv,
                                                             Qhi,Qlo, Khi,Klo, Vthi,Vtlo);
  stats_kernel <<<dim3(NP/128, ISPL, NB),  256, 0, stream>>>(Qhi,Qlo, Khi,Klo, colpart);
  scalev_kernel<<<dim3(n/(256*8)),         256, 0, stream>>>(Vthi, Vtlo, colpart);
  attn_kernel  <<<dim3(NP/128, JSPL, NB),  256, 0, stream>>>(Qhi,Qlo, Khi,Klo,
                                                             Vthi,Vtlo, xacc);
  final_kernel <<<dim3(n/(256*4)),         256, 0, stream>>>(X, xacc, outp);
}

// Round 10
// 254.416 us; speedup vs baseline: 1.4955x; 1.1123x over previous
//
#include <hip/hip_runtime.h>
#include <hip/hip_bf16.h>

// SelfAttention (B=4, C=128, H=W=64), fp32 I/O.
// out[b,c,i] = X[b,c,i] + sum_j exp(S[i,j]) * rinv_j * V[j,c],
//   S = Q K^T, rinv_j = 1/sum_i exp(S[i,j])   (softmax over query axis)
// S via split-bf16 (hi+lo) 3-term MFMA emulation (precision-critical);
// PV via plain bf16 MFMA (P,V' in [0,1]-ish; 2^-9 quantization is within
// the 0.176 absmax budget). 32x32x16 MFMA, S^T formulation.

typedef unsigned short u16;
typedef __attribute__((ext_vector_type(8))) __bf16 bf16x8;
typedef __attribute__((ext_vector_type(8))) unsigned short us8;
typedef __attribute__((ext_vector_type(4))) float f32x4;
typedef __attribute__((ext_vector_type(16))) float f32x16;

#define NB 4
#define CH 128
#define NP 4096
#define JSPL 4   // attn j-splits (partials into out)
#define ISPL 8   // stats i-splits (partials into colpart)

__device__ __forceinline__ float bf2f(u16 b){ union{float f;unsigned u;}v; v.u=((unsigned)b)<<16; return v.f; }
__device__ __forceinline__ u16 f2bf(float f){ union{float f;unsigned u;}v; v.f=f; unsigned r=v.u + 0x7FFFu + ((v.u>>16)&1u); return (u16)(r>>16); }

__device__ __forceinline__ f32x4 mfma16(bf16x8 a, bf16x8 b, f32x4 c){
  return __builtin_amdgcn_mfma_f32_16x16x32_bf16(a, b, c, 0, 0, 0);
}
__device__ __forceinline__ f32x16 mfma32(bf16x8 a, bf16x8 b, f32x16 c){
  return __builtin_amdgcn_mfma_f32_32x32x16_bf16(a, b, c, 0, 0, 0);
}
__device__ __forceinline__ bf16x8 ld8(const u16* p){
  union { us8 u; bf16x8 b; } v; v.u = *(const us8*)p; return v.b;
}
__device__ __forceinline__ void split8(const float* p, bf16x8& h, bf16x8& l){
  union { us8 u; bf16x8 b; } uh, ul;
  #pragma unroll
  for (int e=0;e<8;++e){
    float f = p[e];
    u16 hb = f2bf(f);
    uh.u[e] = hb;
    ul.u[e] = f2bf(f - bf2f(hb));
  }
  h = uh.b; l = ul.b;
}
// pack (a,b) -> bf16 pair dword, RNE
__device__ __forceinline__ unsigned pk2(float a, float b){
  float2 f2; f2.x = a; f2.y = b;
  __hip_bfloat162 hb = __float22bfloat162_rn(f2);
  unsigned u; __builtin_memcpy(&u, &hb, 4);
  return u;
}
__device__ __forceinline__ void gll16(const void* g, void* l){
  __builtin_amdgcn_global_load_lds((const __attribute__((address_space(1))) void*)g,
                                   (__attribute__((address_space(3))) void*)l, 16, 0, 0);
}

// ---------------------------------------------------------------------------
// Kernel 0: pre-split the three 128x128 weight matrices into bf16 hi/lo.
// ---------------------------------------------------------------------------
__global__ __launch_bounds__(256) void wsplit_kernel(
    const float* __restrict__ Wq, const float* __restrict__ Wk,
    const float* __restrict__ Wv, u16* __restrict__ Whi, u16* __restrict__ Wlo)
{
  const int m = blockIdx.y;
  const float* W = (m==0) ? Wq : (m==1) ? Wk : Wv;
  int i = blockIdx.x*256 + threadIdx.x;
  float f = W[i];
  u16 hb = f2bf(f);
  Whi[m*CH*CH + i] = hb;
  Wlo[m*CH*CH + i] = f2bf(f - bf2f(hb));
}

// ---------------------------------------------------------------------------
// Kernel 1: projections (one wave per 16-pixel tile), 16x16x32 MFMA.
// Q/K stored [b][i][ch] hi/lo; V stored transposed [b][c][j] hi/lo.
// ---------------------------------------------------------------------------
__global__ __launch_bounds__(64) void proj_kernel(
    const float* __restrict__ X,
    const u16* __restrict__ Whi, const u16* __restrict__ Wlo,
    const float* __restrict__ bq, const float* __restrict__ bk,
    const float* __restrict__ bv,
    u16* __restrict__ Qhi, u16* __restrict__ Qlo,
    u16* __restrict__ Khi, u16* __restrict__ Klo,
    u16* __restrict__ Vthi, u16* __restrict__ Vtlo)
{
  __shared__ float XT[16][CH+4];
  const int b = blockIdx.y, p0 = blockIdx.x*16, lane = threadIdx.x;
  #pragma unroll
  for (int h=0; h<2; ++h){
    int c = lane + h*64;
    const float* src = X + ((size_t)b*CH + c)*NP + p0;
    #pragma unroll
    for (int v4=0; v4<4; ++v4){
      f32x4 v = *(const f32x4*)(src + v4*4);
      #pragma unroll
      for (int p=0;p<4;++p) XT[v4*4+p][c] = v[p];
    }
  }
  __syncthreads();
  const int l15 = lane&15, quad = lane>>4;
  bf16x8 xh[4], xl[4];
  #pragma unroll
  for (int s=0;s<4;++s) split8(&XT[l15][s*32+quad*8], xh[s], xl[s]);

  const float* bm[2] = {bq, bk};
  u16* OH[2] = {Qhi, Khi};
  u16* OL[2] = {Qlo, Klo};
  #pragma unroll
  for (int m=0;m<2;++m){
    const u16* WH = Whi + m*CH*CH;
    const u16* WL = Wlo + m*CH*CH;
    #pragma unroll
    for (int nt=0;nt<8;++nt){
      f32x4 a = {0.f,0.f,0.f,0.f};
      #pragma unroll
      for (int s=0;s<4;++s){
        size_t g = (size_t)(nt*16+l15)*CH + s*32 + quad*8;
        bf16x8 wh = ld8(&WH[g]), wl = ld8(&WL[g]);
        a = mfma16(xh[s], wl, a);
        a = mfma16(xl[s], wh, a);
        a = mfma16(xh[s], wh, a);
      }
      int o = nt*16 + l15;
      float bias = bm[m][o];
      #pragma unroll
      for (int r=0;r<4;++r){
        int i = p0 + quad*4 + r;
        float q = a[r] + bias;
        u16 hb = f2bf(q);
        size_t idx = ((size_t)b*NP + i)*CH + o;
        OH[m][idx] = hb;
        OL[m][idx] = f2bf(q - bf2f(hb));
      }
    }
  }
  const u16* WH = Whi + 2*CH*CH;
  const u16* WL = Wlo + 2*CH*CH;
  #pragma unroll
  for (int mt=0;mt<8;++mt){
    f32x4 a = {0.f,0.f,0.f,0.f};
    #pragma unroll
    for (int s=0;s<4;++s){
      size_t g = (size_t)(mt*16+l15)*CH + s*32 + quad*8;
      bf16x8 wh = ld8(&WH[g]), wl = ld8(&WL[g]);
      a = mfma16(wh, xl[s], a);
      a = mfma16(wl, xh[s], a);
      a = mfma16(wh, xh[s], a);
    }
    #pragma unroll
    for (int r=0;r<4;++r){
      int co = mt*16 + quad*4 + r;
      float v = a[r] + bv[co];
      u16 hb = f2bf(v);
      size_t idx = ((size_t)b*CH + co)*NP + p0 + l15;
      Vthi[idx] = hb;
      Vtlo[idx] = f2bf(v - bf2f(hb));
    }
  }
}

// ---------------------------------------------------------------------------
// Kernel 2: partial column sums via S^T = K Q^T with 32x32x16 MFMA.
// K frags register-resident; Q chunks LDS-staged (dbuf), software-pipelined.
// colpart[isplit][b][j] = sum_{i in chunk} exp(S[i][j])
// ---------------------------------------------------------------------------
__global__ __launch_bounds__(256,3) void stats_kernel(
    const u16* __restrict__ Qhi, const u16* __restrict__ Qlo,
    const u16* __restrict__ Khi, const u16* __restrict__ Klo,
    float* __restrict__ colpart)
{
  __shared__ u16 SQ[2][2][32*CH];   // [buf][hi/lo][chunk(c16)*32 + row] * 8
  const int b = blockIdx.z, isplit = blockIdx.y;
  const int tid = threadIdx.x, lane = tid&63, w = tid>>6;
  const int l31 = lane&31, h = lane>>5;
  const int j0w = blockIdx.x*128 + w*32;

  const int slot0 = w*128 + lane, slot1 = slot0 + 64;
  const int qr0 = slot0&31, qc0 = slot0>>5, qr1 = slot1&31, qc1 = slot1>>5;
  const size_t qg0 = ((size_t)b*NP + qr0)*CH + qc0*8;
  const size_t qg1 = ((size_t)b*NP + qr1)*CH + qc1*8;
  const int lof0 = slot0*8, lof1 = slot1*8;

  // K fragments register-resident: A[m=j=l31][k=ks*16+h*8+e]
  bf16x8 kh[8], kl[8];
  #pragma unroll
  for (int ks=0;ks<8;++ks){
    size_t g = ((size_t)b*NP + j0w + l31)*CH + ks*16 + h*8;
    kh[ks] = ld8(&Khi[g]);
    kl[ks] = ld8(&Klo[g]);
  }

  const int ibase = isplit*(NP/ISPL);
  const int NCH = (NP/ISPL)/32;     // 16 chunks

  auto stageQ = [&](int t){
    size_t iofs = (size_t)(ibase + t*32)*CH;
    int bf = t&1;
    gll16(&Qhi[qg0 + iofs], &SQ[bf][0][lof0]);
    gll16(&Qhi[qg1 + iofs], &SQ[bf][0][lof1]);
    gll16(&Qlo[qg0 + iofs], &SQ[bf][1][lof0]);
    gll16(&Qlo[qg1 + iofs], &SQ[bf][1][lof1]);
  };
  auto computeS = [&](int t, f32x16& s){
    const u16* Qh = &SQ[t&1][0][0];
    const u16* Ql = &SQ[t&1][1][0];
    #pragma unroll
    for (int r=0;r<16;++r) s[r] = 0.f;
    #pragma unroll
    for (int ks=0;ks<8;++ks){
      int o = (ks*2+h)*256 + l31*8;      // B[k][n=i=l31]
      bf16x8 qbh = ld8(&Qh[o]);
      bf16x8 qbl = ld8(&Ql[o]);
      s = mfma32(kh[ks], qbl, s);
      s = mfma32(kl[ks], qbh, s);
      s = mfma32(kh[ks], qbh, s);
    }
  };

  stageQ(0); stageQ(1);
  __syncthreads();                  // chunks 0,1 staged
  f32x16 s;
  computeS(0, s);
  __syncthreads();                  // all waves done reading SQ[0]

  float scol[16];
  #pragma unroll
  for (int r=0;r<16;++r) scol[r] = 0.f;

  for (int ic=0; ic<NCH; ++ic){
    if (ic+2 < NCH) stageQ(ic+2);   // -> SQ[ic&1], safe after prev barrier
    #pragma unroll
    for (int r=0;r<16;++r) scol[r] += __expf(s[r]);
    if (ic+1 < NCH) computeS(ic+1, s); // reads SQ[(ic+1)&1], staged+drained
    __syncthreads();
  }
  // reduce over the 32 i-lanes (same h keeps same j)
  #pragma unroll
  for (int m=1; m<32; m<<=1){
    #pragma unroll
    for (int r=0;r<16;++r) scol[r] += __shfl_xor(scol[r], m);
  }
  if (l31 == 0){
    #pragma unroll
    for (int r=0;r<16;++r){
      int j = j0w + (r&3) + 8*(r>>2) + 4*h;
      colpart[((size_t)(isplit*NB + b))*NP + j] = scol[r];
    }
  }
}

// ---------------------------------------------------------------------------
// Kernel 3: V' = rinv_j * V -> bf16 (hi only; PV runs plain bf16).
// rinv computed inline from the ISPL colpart partials.
// ---------------------------------------------------------------------------
__global__ __launch_bounds__(256) void scalev_kernel(
    u16* __restrict__ Vthi, const u16* __restrict__ Vtlo,
    const float* __restrict__ colpart)
{
  size_t t = (size_t)blockIdx.x*256 + threadIdx.x;
  size_t base = t*8;
  int bc = (int)(base >> 12);
  int b  = bc >> 7;
  int j0 = (int)(base & (NP-1));
  f32x4 s0 = {0.f,0.f,0.f,0.f}, s1 = {0.f,0.f,0.f,0.f};
  #pragma unroll
  for (int k=0;k<ISPL;++k){
    const float* cp = &colpart[((size_t)(k*NB + b))*NP + j0];
    f32x4 a0 = *(const f32x4*)cp;
    f32x4 a1 = *(const f32x4*)(cp+4);
    #pragma unroll
    for (int e=0;e<4;++e){ s0[e]+=a0[e]; s1[e]+=a1[e]; }
  }
  us8 hh = *(const us8*)&Vthi[base];
  us8 ll = *(const us8*)&Vtlo[base];
  us8 oh;
  #pragma unroll
  for (int e=0;e<8;++e){
    float r = 1.0f / (e<4 ? s0[e] : s1[e-4]);
    float v = (bf2f(hh[e]) + bf2f(ll[e])) * r;
    oh[e] = f2bf(v);
  }
  *(us8*)&Vthi[base] = oh;
}

// ---------------------------------------------------------------------------
// Kernel 4: out := X   (seed for attn's atomic accumulation)
// ---------------------------------------------------------------------------
__global__ __launch_bounds__(256) void copyx_kernel(
    const float* __restrict__ X, float* __restrict__ out)
{
  size_t idx = ((size_t)blockIdx.x*256 + threadIdx.x)*4;
  *(f32x4*)&out[idx] = *(const f32x4*)&X[idx];
}

// ---------------------------------------------------------------------------
// Kernel 5: flash attn. S^T 3-term split-bf16; PV plain bf16 (1 MFMA).
// Software-pipelined, K staged 2 ahead / V 1 ahead, 1 barrier per j-tile.
// Accumulates directly into out (pre-seeded with X) via fp32 atomics.
// ---------------------------------------------------------------------------
__global__ __launch_bounds__(256,2) void attn_kernel(
    const u16* __restrict__ Qhi, const u16* __restrict__ Qlo,
    const u16* __restrict__ Khi, const u16* __restrict__ Klo,
    const u16* __restrict__ Vthi,
    float* __restrict__ out)
{
  __shared__ u16 SK[2][2][32*CH];    // [buf][hi/lo][chunk(c16)*32 + row] * 8
  __shared__ u16 SV[2][4*CH*8];      // [buf][chunk(c4)*128 + row] * 8 (hi only)
  const int b = blockIdx.z, jsplit = blockIdx.y;
  const int tid = threadIdx.x, lane = tid&63, w = tid>>6;
  const int l31 = lane&31, h = lane>>5;
  const int i0w = blockIdx.x*128 + w*32;
  const bool hb1 = (h != 0);

  // staging: 512 slots of 16B per array-half, 2 per thread
  const int slot0 = tid, slot1 = tid + 256;
  const int kr0 = slot0&31, kc0 = slot0>>5, kr1 = slot1&31, kc1 = slot1>>5;
  const int vr0 = slot0&127, vc0 = slot0>>7, vr1 = slot1&127, vc1 = slot1>>7;
  const size_t kg0 = ((size_t)b*NP + kr0)*CH + kc0*8;
  const size_t kg1 = ((size_t)b*NP + kr1)*CH + kc1*8;
  const size_t vg0 = ((size_t)b*CH + vr0)*NP + vc0*8;
  const size_t vg1 = ((size_t)b*CH + vr1)*NP + vc1*8;
  const int lof0 = slot0*8, lof1 = slot1*8;

  const int jbase = jsplit*(NP/JSPL);
  const int NJT = (NP/JSPL)/32;      // 32 j-tiles

  auto stageK = [&](int t){
    size_t jofs = (size_t)(jbase + t*32)*CH;
    int bf = t&1;
    gll16(&Khi[kg0 + jofs], &SK[bf][0][lof0]);
    gll16(&Khi[kg1 + jofs], &SK[bf][0][lof1]);
    gll16(&Klo[kg0 + jofs], &SK[bf][1][lof0]);
    gll16(&Klo[kg1 + jofs], &SK[bf][1][lof1]);
  };
  auto stageV = [&](int t){
    int j0 = jbase + t*32;
    int bf = t&1;
    gll16(&Vthi[vg0 + j0], &SV[bf][lof0]);
    gll16(&Vthi[vg1 + j0], &SV[bf][lof1]);
  };

  // Q B-fragments resident: B[k=ks*16+h*8+e][n=i=l31]
  bf16x8 qh[8], ql[8];
  #pragma unroll
  for (int ks=0;ks<8;++ks){
    size_t g = ((size_t)b*NP + i0w + l31)*CH + ks*16 + h*8;
    qh[ks] = ld8(&Qhi[g]); ql[ks] = ld8(&Qlo[g]);
  }

  auto computeS = [&](int t, f32x16& s){
    const u16* Kh = &SK[t&1][0][0];
    const u16* Kl = &SK[t&1][1][0];
    #pragma unroll
    for (int r=0;r<16;++r) s[r] = 0.f;
    #pragma unroll
    for (int ks=0;ks<8;++ks){
      int o = (ks*2+h)*256 + l31*8;
      bf16x8 ah = ld8(&Kh[o]);
      bf16x8 al = ld8(&Kl[o]);
      s = mfma32(ah, ql[ks], s);
      s = mfma32(al, qh[ks], s);
      s = mfma32(ah, qh[ks], s);
    }
  };

  f32x16 acc[4];
  #pragma unroll
  for (int mt=0;mt<4;++mt)
    #pragma unroll
    for (int r=0;r<16;++r) acc[mt][r] = 0.f;

  // prologue: tile0 (K+V) and tile1 (K) staged; S(0) computed
  stageK(0); stageV(0); stageK(1);
  __syncthreads();                   // tiles staged (vmcnt drained)
  f32x16 s;
  computeS(0, s);
  __syncthreads();                   // all waves done reading SK[0]

  for (int jt=0; jt<NJT; ++jt){
    const int cb = jt&1;
    if (jt+2 < NJT) stageK(jt+2);    // -> SK[cb]   (K(jt) reads done)
    if (jt+1 < NJT) stageV(jt+1);    // -> SV[cb^1] (V(jt-1) reads done)

    float p[16];
    #pragma unroll
    for (int r=0;r<16;++r) p[r] = __expf(s[r]);

    if (jt+1 < NJT) computeS(jt+1, s);   // reads SK[cb^1], staged+drained

    const u16* Vh = &SV[cb][0];
    // two k-tiles of 16 j each: assemble P^T B-frags in-register (hi only)
    #pragma unroll
    for (int t=0;t<2;++t){
      unsigned hA = pk2(p[8*t+0], p[8*t+1]);
      unsigned hB = pk2(p[8*t+2], p[8*t+3]);
      unsigned hC = pk2(p[8*t+4], p[8*t+5]);
      unsigned hD = pk2(p[8*t+6], p[8*t+7]);
      unsigned s0h = hb1? hA:hC, s1h = hb1? hB:hD;
      unsigned r0h = __shfl_xor(s0h, 32), r1h = __shfl_xor(s1h, 32);
      unsigned dh[4];
      dh[0] = hb1? r0h : hA;  dh[1] = hb1? r1h : hB;
      dh[2] = hb1? hC  : r0h; dh[3] = hb1? hD  : r1h;
      bf16x8 Bh;
      __builtin_memcpy(&Bh, dh, 16);
      // PV: A = V'^T[m=c][k=j], B = P^T -> acc[c][i]
      #pragma unroll
      for (int mt=0;mt<4;++mt){
        int o = (t*2+h)*1024 + (mt*32+l31)*8;
        bf16x8 vh = ld8(&Vh[o]);
        acc[mt] = mfma32(vh, Bh, acc[mt]);
      }
    }
    __syncthreads();                 // buf free + next staging drained
  }
  // epilogue: acc[mt][r] = O^T[c][i], c = mt*32+(r&3)+8*(r>>2)+4*h, i = i0w+l31
  float* xp = out + (size_t)b*CH*NP;
  #pragma unroll
  for (int mt=0;mt<4;++mt){
    #pragma unroll
    for (int r=0;r<16;++r){
      int c = mt*32 + (r&3) + 8*(r>>2) + 4*h;
      atomicAdd(&xp[(size_t)c*NP + i0w + l31], acc[mt][r]);
    }
  }
}

extern "C" void kernel_launch(void* const* d_in, const int* in_sizes, int n_in,
                              void* d_out, int out_size, void* d_ws, size_t ws_size,
                              hipStream_t stream)
{
  const float* X  = (const float*)d_in[0];
  const float* Wq = (const float*)d_in[1];
  const float* bq = (const float*)d_in[2];
  const float* Wk = (const float*)d_in[3];
  const float* bk = (const float*)d_in[4];
  const float* Wv = (const float*)d_in[5];
  const float* bv = (const float*)d_in[6];
  float* outp = (float*)d_out;

  const size_t n = (size_t)NB*NP*CH;        // 2,097,152
  u16* Qhi = (u16*)d_ws;
  u16* Qlo = Qhi + n;
  u16* Khi = Qlo + n;
  u16* Klo = Khi + n;
  u16* Vthi = Klo + n;
  u16* Vtlo = Vthi + n;
  u16* Whi  = Vtlo + n;
  u16* Wlo  = Whi + 3*CH*CH;
  float* colpart = (float*)(Wlo + 3*CH*CH);      // ISPL*NB*NP

  wsplit_kernel<<<dim3(CH*CH/256, 3),      256, 0, stream>>>(Wq, Wk, Wv, Whi, Wlo);
  proj_kernel  <<<dim3(NP/16, NB),          64, 0, stream>>>(X, Whi, Wlo, bq, bk, bv,
                                                             Qhi,Qlo, Khi,Klo, Vthi,Vtlo);
  stats_kernel <<<dim3(NP/128, ISPL, NB),  256, 0, stream>>>(Qhi,Qlo, Khi,Klo, colpart);
  scalev_kernel<<<dim3(n/(256*8)),         256, 0, stream>>>(Vthi, Vtlo, colpart);
  copyx_kernel <<<dim3(n/(256*4)),         256, 0, stream>>>(X, outp);
  attn_kernel  <<<dim3(NP/128, JSPL, NB),  256, 0, stream>>>(Qhi,Qlo, Khi,Klo,
                                                             Vthi, outp);
}

// Round 11
// 250.151 us; speedup vs baseline: 1.5210x; 1.0170x over previous
//
#include <hip/hip_runtime.h>
#include <hip/hip_bf16.h>

// SelfAttention (B=4, C=128, H=W=64), fp32 I/O.
// out[b,c,i] = X[b,c,i] + sum_j exp(S[i,j]) * rinv_j * V[j,c],
//   S = Q K^T, rinv_j = 1/sum_i exp(S[i,j])   (softmax over query axis)
// S via split-bf16 (hi+lo) 3-term MFMA emulation (precision-critical).
// P = exp(S) materialized in bf16 B-fragment layout by stats; attn is a
// pure P@V' streaming GEMM (PV plain bf16). Fallback (small ws): r10 flash.

typedef unsigned short u16;
typedef __attribute__((ext_vector_type(8))) __bf16 bf16x8;
typedef __attribute__((ext_vector_type(8))) unsigned short us8;
typedef __attribute__((ext_vector_type(4))) float f32x4;
typedef __attribute__((ext_vector_type(16))) float f32x16;

#define NB 4
#define CH 128
#define NP 4096
#define ISPL 8    // stats i-splits
#define JSPLF 4   // fallback attn j-splits
#define JSPLP 8   // P-path attn j-splits

__device__ __forceinline__ float bf2f(u16 b){ union{float f;unsigned u;}v; v.u=((unsigned)b)<<16; return v.f; }
__device__ __forceinline__ u16 f2bf(float f){ union{float f;unsigned u;}v; v.f=f; unsigned r=v.u + 0x7FFFu + ((v.u>>16)&1u); return (u16)(r>>16); }

__device__ __forceinline__ f32x4 mfma16(bf16x8 a, bf16x8 b, f32x4 c){
  return __builtin_amdgcn_mfma_f32_16x16x32_bf16(a, b, c, 0, 0, 0);
}
__device__ __forceinline__ f32x16 mfma32(bf16x8 a, bf16x8 b, f32x16 c){
  return __builtin_amdgcn_mfma_f32_32x32x16_bf16(a, b, c, 0, 0, 0);
}
__device__ __forceinline__ bf16x8 ld8(const u16* p){
  union { us8 u; bf16x8 b; } v; v.u = *(const us8*)p; return v.b;
}
__device__ __forceinline__ void split8(const float* p, bf16x8& h, bf16x8& l){
  union { us8 u; bf16x8 b; } uh, ul;
  #pragma unroll
  for (int e=0;e<8;++e){
    float f = p[e];
    u16 hb = f2bf(f);
    uh.u[e] = hb;
    ul.u[e] = f2bf(f - bf2f(hb));
  }
  h = uh.b; l = ul.b;
}
__device__ __forceinline__ unsigned pk2(float a, float b){
  float2 f2; f2.x = a; f2.y = b;
  __hip_bfloat162 hb = __float22bfloat162_rn(f2);
  unsigned u; __builtin_memcpy(&u, &hb, 4);
  return u;
}
// C/D-layout p[8] (one k-tile) -> P^T B-fragment (lane n=i, k=h*8+e), via
// cross-half shfl. Verified layout (r4..r10).
__device__ __forceinline__ us8 pfrag(const float* p, bool hb1){
  unsigned hA = pk2(p[0], p[1]);
  unsigned hB = pk2(p[2], p[3]);
  unsigned hC = pk2(p[4], p[5]);
  unsigned hD = pk2(p[6], p[7]);
  unsigned s0h = hb1? hA:hC, s1h = hb1? hB:hD;
  unsigned r0h = __shfl_xor(s0h, 32), r1h = __shfl_xor(s1h, 32);
  unsigned dh[4];
  dh[0] = hb1? r0h : hA;  dh[1] = hb1? r1h : hB;
  dh[2] = hb1? hC  : r0h; dh[3] = hb1? hD  : r1h;
  us8 o; __builtin_memcpy(&o, dh, 16); return o;
}
__device__ __forceinline__ void gll16(const void* g, void* l){
  __builtin_amdgcn_global_load_lds((const __attribute__((address_space(1))) void*)g,
                                   (__attribute__((address_space(3))) void*)l, 16, 0, 0);
}

// ---------------------------------------------------------------------------
// Kernel 0: pre-split the three 128x128 weight matrices into bf16 hi/lo.
// ---------------------------------------------------------------------------
__global__ __launch_bounds__(256) void wsplit_kernel(
    const float* __restrict__ Wq, const float* __restrict__ Wk,
    const float* __restrict__ Wv, u16* __restrict__ Whi, u16* __restrict__ Wlo)
{
  const int m = blockIdx.y;
  const float* W = (m==0) ? Wq : (m==1) ? Wk : Wv;
  int i = blockIdx.x*256 + threadIdx.x;
  float f = W[i];
  u16 hb = f2bf(f);
  Whi[m*CH*CH + i] = hb;
  Wlo[m*CH*CH + i] = f2bf(f - bf2f(hb));
}

// ---------------------------------------------------------------------------
// Kernel 1: projections (one wave per 16-pixel tile), 16x16x32 MFMA.
// ---------------------------------------------------------------------------
__global__ __launch_bounds__(64) void proj_kernel(
    const float* __restrict__ X,
    const u16* __restrict__ Whi, const u16* __restrict__ Wlo,
    const float* __restrict__ bq, const float* __restrict__ bk,
    const float* __restrict__ bv,
    u16* __restrict__ Qhi, u16* __restrict__ Qlo,
    u16* __restrict__ Khi, u16* __restrict__ Klo,
    u16* __restrict__ Vthi, u16* __restrict__ Vtlo)
{
  __shared__ float XT[16][CH+4];
  const int b = blockIdx.y, p0 = blockIdx.x*16, lane = threadIdx.x;
  #pragma unroll
  for (int h=0; h<2; ++h){
    int c = lane + h*64;
    const float* src = X + ((size_t)b*CH + c)*NP + p0;
    #pragma unroll
    for (int v4=0; v4<4; ++v4){
      f32x4 v = *(const f32x4*)(src + v4*4);
      #pragma unroll
      for (int p=0;p<4;++p) XT[v4*4+p][c] = v[p];
    }
  }
  __syncthreads();
  const int l15 = lane&15, quad = lane>>4;
  bf16x8 xh[4], xl[4];
  #pragma unroll
  for (int s=0;s<4;++s) split8(&XT[l15][s*32+quad*8], xh[s], xl[s]);

  const float* bm[2] = {bq, bk};
  u16* OH[2] = {Qhi, Khi};
  u16* OL[2] = {Qlo, Klo};
  #pragma unroll
  for (int m=0;m<2;++m){
    const u16* WH = Whi + m*CH*CH;
    const u16* WL = Wlo + m*CH*CH;
    #pragma unroll
    for (int nt=0;nt<8;++nt){
      f32x4 a = {0.f,0.f,0.f,0.f};
      #pragma unroll
      for (int s=0;s<4;++s){
        size_t g = (size_t)(nt*16+l15)*CH + s*32 + quad*8;
        bf16x8 wh = ld8(&WH[g]), wl = ld8(&WL[g]);
        a = mfma16(xh[s], wl, a);
        a = mfma16(xl[s], wh, a);
        a = mfma16(xh[s], wh, a);
      }
      int o = nt*16 + l15;
      float bias = bm[m][o];
      #pragma unroll
      for (int r=0;r<4;++r){
        int i = p0 + quad*4 + r;
        float q = a[r] + bias;
        u16 hb = f2bf(q);
        size_t idx = ((size_t)b*NP + i)*CH + o;
        OH[m][idx] = hb;
        OL[m][idx] = f2bf(q - bf2f(hb));
      }
    }
  }
  const u16* WH = Whi + 2*CH*CH;
  const u16* WL = Wlo + 2*CH*CH;
  #pragma unroll
  for (int mt=0;mt<8;++mt){
    f32x4 a = {0.f,0.f,0.f,0.f};
    #pragma unroll
    for (int s=0;s<4;++s){
      size_t g = (size_t)(mt*16+l15)*CH + s*32 + quad*8;
      bf16x8 wh = ld8(&WH[g]), wl = ld8(&WL[g]);
      a = mfma16(wh, xl[s], a);
      a = mfma16(wl, xh[s], a);
      a = mfma16(wh, xh[s], a);
    }
    #pragma unroll
    for (int r=0;r<4;++r){
      int co = mt*16 + quad*4 + r;
      float v = a[r] + bv[co];
      u16 hb = f2bf(v);
      size_t idx = ((size_t)b*CH + co)*NP + p0 + l15;
      Vthi[idx] = hb;
      Vtlo[idx] = f2bf(v - bf2f(hb));
    }
  }
}

// ---------------------------------------------------------------------------
// Kernel 2: S^T = K Q^T (32x32x16, 3-term). Column sums always; if STOREP,
// also emit P=exp(S) as bf16 B-fragments to Pbuf[b][jtile][kh(4)][i(4096)]x16B.
// ---------------------------------------------------------------------------
template<bool STOREP>
__global__ __launch_bounds__(256,3) void stats_kernel(
    const u16* __restrict__ Qhi, const u16* __restrict__ Qlo,
    const u16* __restrict__ Khi, const u16* __restrict__ Klo,
    float* __restrict__ colpart, u16* __restrict__ Pbuf)
{
  __shared__ u16 SQ[2][2][32*CH];
  const int b = blockIdx.z, isplit = blockIdx.y;
  const int tid = threadIdx.x, lane = tid&63, w = tid>>6;
  const int l31 = lane&31, h = lane>>5;
  const int j0w = blockIdx.x*128 + w*32;
  const bool hb1 = (h != 0);

  const int slot0 = w*128 + lane, slot1 = slot0 + 64;
  const int qr0 = slot0&31, qc0 = slot0>>5, qr1 = slot1&31, qc1 = slot1>>5;
  const size_t qg0 = ((size_t)b*NP + qr0)*CH + qc0*8;
  const size_t qg1 = ((size_t)b*NP + qr1)*CH + qc1*8;
  const int lof0 = slot0*8, lof1 = slot1*8;

  bf16x8 kh[8], kl[8];
  #pragma unroll
  for (int ks=0;ks<8;++ks){
    size_t g = ((size_t)b*NP + j0w + l31)*CH + ks*16 + h*8;
    kh[ks] = ld8(&Khi[g]);
    kl[ks] = ld8(&Klo[g]);
  }

  const int ibase = isplit*(NP/ISPL);
  const int NCH = (NP/ISPL)/32;     // 16 chunks
  const size_t Pjt = ((size_t)(b*128 + blockIdx.x*4 + w))*((size_t)4*NP*8);

  auto stageQ = [&](int t){
    size_t iofs = (size_t)(ibase + t*32)*CH;
    int bf = t&1;
    gll16(&Qhi[qg0 + iofs], &SQ[bf][0][lof0]);
    gll16(&Qhi[qg1 + iofs], &SQ[bf][0][lof1]);
    gll16(&Qlo[qg0 + iofs], &SQ[bf][1][lof0]);
    gll16(&Qlo[qg1 + iofs], &SQ[bf][1][lof1]);
  };
  auto computeS = [&](int t, f32x16& s){
    const u16* Qh = &SQ[t&1][0][0];
    const u16* Ql = &SQ[t&1][1][0];
    #pragma unroll
    for (int r=0;r<16;++r) s[r] = 0.f;
    #pragma unroll
    for (int ks=0;ks<8;++ks){
      int o = (ks*2+h)*256 + l31*8;
      bf16x8 qbh = ld8(&Qh[o]);
      bf16x8 qbl = ld8(&Ql[o]);
      s = mfma32(kh[ks], qbl, s);
      s = mfma32(kl[ks], qbh, s);
      s = mfma32(kh[ks], qbh, s);
    }
  };

  stageQ(0); stageQ(1);
  __syncthreads();
  f32x16 s;
  computeS(0, s);
  __syncthreads();

  float scol[16];
  #pragma unroll
  for (int r=0;r<16;++r) scol[r] = 0.f;

  for (int ic=0; ic<NCH; ++ic){
    if (ic+2 < NCH) stageQ(ic+2);
    float p[16];
    #pragma unroll
    for (int r=0;r<16;++r){ p[r] = __expf(s[r]); scol[r] += p[r]; }
    if (STOREP){
      int iglob = ibase + ic*32 + l31;
      #pragma unroll
      for (int t=0;t<2;++t){
        us8 frag = pfrag(&p[8*t], hb1);
        *(us8*)&Pbuf[Pjt + ((size_t)((t*2+h)*NP) + iglob)*8] = frag;
      }
    }
    if (ic+1 < NCH) computeS(ic+1, s);
    __syncthreads();
  }
  #pragma unroll
  for (int m=1; m<32; m<<=1){
    #pragma unroll
    for (int r=0;r<16;++r) scol[r] += __shfl_xor(scol[r], m);
  }
  if (l31 == 0){
    #pragma unroll
    for (int r=0;r<16;++r){
      int j = j0w + (r&3) + 8*(r>>2) + 4*h;
      colpart[((size_t)(isplit*NB + b))*NP + j] = scol[r];
    }
  }
}

// ---------------------------------------------------------------------------
// Kernel 3: V' = rinv_j * V -> bf16 (hi only).
// ---------------------------------------------------------------------------
__global__ __launch_bounds__(256) void scalev_kernel(
    u16* __restrict__ Vthi, const u16* __restrict__ Vtlo,
    const float* __restrict__ colpart)
{
  size_t t = (size_t)blockIdx.x*256 + threadIdx.x;
  size_t base = t*8;
  int bc = (int)(base >> 12);
  int b  = bc >> 7;
  int j0 = (int)(base & (NP-1));
  f32x4 s0 = {0.f,0.f,0.f,0.f}, s1 = {0.f,0.f,0.f,0.f};
  #pragma unroll
  for (int k=0;k<ISPL;++k){
    const float* cp = &colpart[((size_t)(k*NB + b))*NP + j0];
    f32x4 a0 = *(const f32x4*)cp;
    f32x4 a1 = *(const f32x4*)(cp+4);
    #pragma unroll
    for (int e=0;e<4;++e){ s0[e]+=a0[e]; s1[e]+=a1[e]; }
  }
  us8 hh = *(const us8*)&Vthi[base];
  us8 ll = *(const us8*)&Vtlo[base];
  us8 oh;
  #pragma unroll
  for (int e=0;e<8;++e){
    float r = 1.0f / (e<4 ? s0[e] : s1[e-4]);
    float v = (bf2f(hh[e]) + bf2f(ll[e])) * r;
    oh[e] = f2bf(v);
  }
  *(us8*)&Vthi[base] = oh;
}

// ---------------------------------------------------------------------------
// Kernel 4: out := X
// ---------------------------------------------------------------------------
__global__ __launch_bounds__(256) void copyx_kernel(
    const float* __restrict__ X, float* __restrict__ out)
{
  size_t idx = ((size_t)blockIdx.x*256 + threadIdx.x)*4;
  *(f32x4*)&out[idx] = *(const f32x4*)&X[idx];
}

// ---------------------------------------------------------------------------
// Kernel 5a (P path): attn = pure P@V' streaming GEMM. P staged from Pbuf
// (already in B-frag image), V' hi staged; dbuf, 1 barrier/jt. JSPLP=8.
// ---------------------------------------------------------------------------
__global__ __launch_bounds__(256,4) void attnp_kernel(
    const u16* __restrict__ Pbuf, const u16* __restrict__ Vthi,
    float* __restrict__ out)
{
  __shared__ u16 SP[2][4*128*8];   // [buf][kh(4)*128 + i_local]*8   (8 KB)
  __shared__ u16 SV[2][4*CH*8];    // [buf][chunk(c4)*128 + c]*8     (8 KB)
  const int b = blockIdx.z, jsplit = blockIdx.y;
  const int tid = threadIdx.x, lane = tid&63, w = tid>>6;
  const int l31 = lane&31, h = lane>>5;
  const int i0blk = blockIdx.x*128;
  const int i0w = i0blk + w*32;

  const int slot1 = tid + 256;
  const size_t vg0 = ((size_t)b*CH + (tid  &127))*NP + (tid  >>7)*8;
  const size_t vg1 = ((size_t)b*CH + (slot1&127))*NP + (slot1>>7)*8;
  const size_t pg0 = (size_t)((tid  >>7)*NP) + i0blk + (tid  &127);
  const size_t pg1 = (size_t)((slot1>>7)*NP) + i0blk + (slot1&127);

  const int NJT = (NP/JSPLP)/32;   // 16

  auto stage = [&](int t){
    int bf = t&1;
    size_t Pjt = ((size_t)(b*128 + jsplit*NJT + t))*((size_t)4*NP*8);
    gll16(&Pbuf[Pjt + pg0*8], &SP[bf][tid*8]);
    gll16(&Pbuf[Pjt + pg1*8], &SP[bf][slot1*8]);
    int j0 = jsplit*(NP/JSPLP) + t*32;
    gll16(&Vthi[vg0 + j0], &SV[bf][tid*8]);
    gll16(&Vthi[vg1 + j0], &SV[bf][slot1*8]);
  };

  f32x16 acc[4];
  #pragma unroll
  for (int mt=0;mt<4;++mt)
    #pragma unroll
    for (int r=0;r<16;++r) acc[mt][r] = 0.f;

  stage(0);
  __syncthreads();

  for (int jt=0; jt<NJT; ++jt){
    const int cb = jt&1;
    if (jt+1 < NJT) stage(jt+1);
    #pragma unroll
    for (int t=0;t<2;++t){
      bf16x8 Bh = ld8(&SP[cb][((t*2+h)*128 + w*32 + l31)*8]);
      #pragma unroll
      for (int mt=0;mt<4;++mt){
        int o = (t*2+h)*1024 + (mt*32+l31)*8;
        bf16x8 vh = ld8(&SV[cb][o]);
        acc[mt] = mfma32(vh, Bh, acc[mt]);
      }
    }
    __syncthreads();
  }
  float* xp = out + (size_t)b*CH*NP;
  #pragma unroll
  for (int mt=0;mt<4;++mt){
    #pragma unroll
    for (int r=0;r<16;++r){
      int c = mt*32 + (r&3) + 8*(r>>2) + 4*h;
      atomicAdd(&xp[(size_t)c*NP + i0w + l31], acc[mt][r]);
    }
  }
}

// ---------------------------------------------------------------------------
// Kernel 5b (fallback, ws too small): r10 flash attn (S recompute in-kernel).
// ---------------------------------------------------------------------------
__global__ __launch_bounds__(256,2) void attnf_kernel(
    const u16* __restrict__ Qhi, const u16* __restrict__ Qlo,
    const u16* __restrict__ Khi, const u16* __restrict__ Klo,
    const u16* __restrict__ Vthi,
    float* __restrict__ out)
{
  __shared__ u16 SK[2][2][32*CH];
  __shared__ u16 SV[2][4*CH*8];
  const int b = blockIdx.z, jsplit = blockIdx.y;
  const int tid = threadIdx.x, lane = tid&63, w = tid>>6;
  const int l31 = lane&31, h = lane>>5;
  const int i0w = blockIdx.x*128 + w*32;
  const bool hb1 = (h != 0);

  const int slot0 = tid, slot1 = tid + 256;
  const int kr0 = slot0&31, kc0 = slot0>>5, kr1 = slot1&31, kc1 = slot1>>5;
  const size_t kg0 = ((size_t)b*NP + kr0)*CH + kc0*8;
  const size_t kg1 = ((size_t)b*NP + kr1)*CH + kc1*8;
  const size_t vg0 = ((size_t)b*CH + (slot0&127))*NP + (slot0>>7)*8;
  const size_t vg1 = ((size_t)b*CH + (slot1&127))*NP + (slot1>>7)*8;
  const int lof0 = slot0*8, lof1 = slot1*8;

  const int jbase = jsplit*(NP/JSPLF);
  const int NJT = (NP/JSPLF)/32;

  auto stageK = [&](int t){
    size_t jofs = (size_t)(jbase + t*32)*CH;
    int bf = t&1;
    gll16(&Khi[kg0 + jofs], &SK[bf][0][lof0]);
    gll16(&Khi[kg1 + jofs], &SK[bf][0][lof1]);
    gll16(&Klo[kg0 + jofs], &SK[bf][1][lof0]);
    gll16(&Klo[kg1 + jofs], &SK[bf][1][lof1]);
  };
  auto stageV = [&](int t){
    int j0 = jbase + t*32;
    int bf = t&1;
    gll16(&Vthi[vg0 + j0], &SV[bf][lof0]);
    gll16(&Vthi[vg1 + j0], &SV[bf][lof1]);
  };

  bf16x8 qh[8], ql[8];
  #pragma unroll
  for (int ks=0;ks<8;++ks){
    size_t g = ((size_t)b*NP + i0w + l31)*CH + ks*16 + h*8;
    qh[ks] = ld8(&Qhi[g]); ql[ks] = ld8(&Qlo[g]);
  }

  auto computeS = [&](int t, f32x16& s){
    const u16* Kh = &SK[t&1][0][0];
    const u16* Kl = &SK[t&1][1][0];
    #pragma unroll
    for (int r=0;r<16;++r) s[r] = 0.f;
    #pragma unroll
    for (int ks=0;ks<8;++ks){
      int o = (ks*2+h)*256 + l31*8;
      bf16x8 ah = ld8(&Kh[o]);
      bf16x8 al = ld8(&Kl[o]);
      s = mfma32(ah, ql[ks], s);
      s = mfma32(al, qh[ks], s);
      s = mfma32(ah, qh[ks], s);
    }
  };

  f32x16 acc[4];
  #pragma unroll
  for (int mt=0;mt<4;++mt)
    #pragma unroll
    for (int r=0;r<16;++r) acc[mt][r] = 0.f;

  stageK(0); stageV(0); stageK(1);
  __syncthreads();
  f32x16 s;
  computeS(0, s);
  __syncthreads();

  for (int jt=0; jt<NJT; ++jt){
    const int cb = jt&1;
    if (jt+2 < NJT) stageK(jt+2);
    if (jt+1 < NJT) stageV(jt+1);

    float p[16];
    #pragma unroll
    for (int r=0;r<16;++r) p[r] = __expf(s[r]);

    if (jt+1 < NJT) computeS(jt+1, s);

    const u16* Vh = &SV[cb][0];
    #pragma unroll
    for (int t=0;t<2;++t){
      us8 fr = pfrag(&p[8*t], hb1);
      bf16x8 Bh; __builtin_memcpy(&Bh, &fr, 16);
      #pragma unroll
      for (int mt=0;mt<4;++mt){
        int o = (t*2+h)*1024 + (mt*32+l31)*8;
        bf16x8 vh = ld8(&Vh[o]);
        acc[mt] = mfma32(vh, Bh, acc[mt]);
      }
    }
    __syncthreads();
  }
  float* xp = out + (size_t)b*CH*NP;
  #pragma unroll
  for (int mt=0;mt<4;++mt){
    #pragma unroll
    for (int r=0;r<16;++r){
      int c = mt*32 + (r&3) + 8*(r>>2) + 4*h;
      atomicAdd(&xp[(size_t)c*NP + i0w + l31], acc[mt][r]);
    }
  }
}

extern "C" void kernel_launch(void* const* d_in, const int* in_sizes, int n_in,
                              void* d_out, int out_size, void* d_ws, size_t ws_size,
                              hipStream_t stream)
{
  const float* X  = (const float*)d_in[0];
  const float* Wq = (const float*)d_in[1];
  const float* bq = (const float*)d_in[2];
  const float* Wk = (const float*)d_in[3];
  const float* bk = (const float*)d_in[4];
  const float* Wv = (const float*)d_in[5];
  const float* bv = (const float*)d_in[6];
  float* outp = (float*)d_out;

  const size_t n = (size_t)NB*NP*CH;        // 2,097,152
  u16* Qhi = (u16*)d_ws;
  u16* Qlo = Qhi + n;
  u16* Khi = Qlo + n;
  u16* Klo = Khi + n;
  u16* Vthi = Klo + n;
  u16* Vtlo = Vthi + n;
  u16* Whi  = Vtlo + n;
  u16* Wlo  = Whi + 3*CH*CH;
  float* colpart = (float*)(Wlo + 3*CH*CH);      // ISPL*NB*NP floats
  u16* Pbuf = (u16*)(colpart + (size_t)ISPL*NB*NP);

  const size_t pelems = (size_t)NB*128*4*NP*8;   // 67,108,864 u16 = 128 MiB
  const size_t need = (size_t)((char*)Pbuf - (char*)d_ws) + pelems*sizeof(u16);
  const bool usep = (ws_size >= need);

  wsplit_kernel<<<dim3(CH*CH/256, 3),      256, 0, stream>>>(Wq, Wk, Wv, Whi, Wlo);
  proj_kernel  <<<dim3(NP/16, NB),          64, 0, stream>>>(X, Whi, Wlo, bq, bk, bv,
                                                             Qhi,Qlo, Khi,Klo, Vthi,Vtlo);
  if (usep){
    stats_kernel<true><<<dim3(NP/128, ISPL, NB), 256, 0, stream>>>(
        Qhi,Qlo, Khi,Klo, colpart, Pbuf);
    scalev_kernel<<<dim3(n/(256*8)),       256, 0, stream>>>(Vthi, Vtlo, colpart);
    copyx_kernel <<<dim3(n/(256*4)),       256, 0, stream>>>(X, outp);
    attnp_kernel <<<dim3(NP/128, JSPLP, NB), 256, 0, stream>>>(Pbuf, Vthi, outp);
  } else {
    stats_kernel<false><<<dim3(NP/128, ISPL, NB), 256, 0, stream>>>(
        Qhi,Qlo, Khi,Klo, colpart, Pbuf);
    scalev_kernel<<<dim3(n/(256*8)),       256, 0, stream>>>(Vthi, Vtlo, colpart);
    copyx_kernel <<<dim3(n/(256*4)),       256, 0, stream>>>(X, outp);
    attnf_kernel <<<dim3(NP/128, JSPLF, NB), 256, 0, stream>>>(
        Qhi,Qlo, Khi,Klo, Vthi, outp);
  }
}